// Round 1
// baseline (976.843 us; speedup 1.0000x reference)
//
#include <hip/hip_runtime.h>
#include <hip/hip_bf16.h>

#define NNODES 20000
#define NEDGES 320000
#define XW 1005          // x row width: 1 + 1000 + 1 + 3

// ---------------- CSR build ----------------

__global__ void edge_deg_kernel(const int* __restrict__ ei, const float* __restrict__ ea,
                                float* __restrict__ deg, int* __restrict__ counts, int E) {
    int e = blockIdx.x * 256 + threadIdx.x;
    if (e >= E) return;
    int dst = ei[E + e];
    atomicAdd(&deg[dst], ea[e]);
    atomicAdd(&counts[dst], 1);
}

__global__ void dinv_kernel(const float* __restrict__ deg, float* __restrict__ dinv, int n) {
    int i = blockIdx.x * 256 + threadIdx.x;
    if (i >= n) return;
    float d = deg[i] + 1.0f;
    dinv[i] = 1.0f / sqrtf(d);
}

__global__ __launch_bounds__(1024) void scan_kernel(const int* __restrict__ counts,
                                                    int* __restrict__ offs, int n) {
    __shared__ int sh[1024];
    __shared__ int carry_s;
    int t = threadIdx.x;
    if (t == 0) carry_s = 0;
    __syncthreads();
    for (int base = 0; base < n; base += 1024) {
        int i = base + t;
        int v = (i < n) ? counts[i] : 0;
        sh[t] = v;
        __syncthreads();
        for (int off = 1; off < 1024; off <<= 1) {
            int add = (t >= off) ? sh[t - off] : 0;
            __syncthreads();
            sh[t] += add;
            __syncthreads();
        }
        int carry = carry_s;
        if (i < n) offs[i] = carry + sh[t] - v;   // exclusive
        __syncthreads();
        if (t == 1023) carry_s = carry + sh[1023];
        __syncthreads();
    }
    if (t == 0) offs[n] = carry_s;
}

__global__ void scatter_kernel(const int* __restrict__ ei, const float* __restrict__ ea,
                               const float* __restrict__ dinv, const int* __restrict__ offs,
                               int* __restrict__ cursor, int* __restrict__ csr_src,
                               float* __restrict__ csr_norm, int E) {
    int e = blockIdx.x * 256 + threadIdx.x;
    if (e >= E) return;
    int src = ei[e];
    int dst = ei[E + e];
    int slot = offs[dst] + atomicAdd(&cursor[dst], 1);
    csr_src[slot] = src;
    csr_norm[slot] = dinv[src] * ea[e] * dinv[dst];
}

// ---------------- embedding indices ----------------

__global__ void idx_kernel(const float* __restrict__ x, int* __restrict__ idx8, int n) {
    int i = blockIdx.x * 256 + threadIdx.x;
    if (i >= n) return;
    const float* r = x + (size_t)i * XW;
    idx8[i * 8 + 0] = (int)(r[0] - 1.0f);                       // li in 0..2
    idx8[i * 8 + 1] = (int)rintf(fabsf(r[1001]) * 10.0f);       // ri in 0..10 (round half-even like jnp.round)
    idx8[i * 8 + 2] = (int)r[1002];
    idx8[i * 8 + 3] = (int)r[1003];
    idx8[i * 8 + 4] = (int)r[1004];
}

// ---------------- table pre-GEMMs: T is (3 + 11 + 3*256) x 512 ----------------
// row 0..2   : layer_table @ W1[0:250]
// row 3..13  : rel_table   @ W1[1250:1500]
// row 14+j*256+v : color_table[v] @ W1[1500+85j : 1585+85j]

__global__ __launch_bounds__(256) void tables_kernel(
    const float* __restrict__ layer_table, const float* __restrict__ rel_table,
    const float* __restrict__ color_table, const float* __restrict__ W1,
    float* __restrict__ T) {
    int g = blockIdx.x * 256 + threadIdx.x;
    if (g >= 782 * 512) return;
    int row = g >> 9, col = g & 511;
    float acc = 0.0f;
    if (row < 3) {
        for (int k = 0; k < 250; ++k)
            acc += layer_table[row * 250 + k] * W1[(size_t)k * 512 + col];
    } else if (row < 14) {
        int r = row - 3;
        for (int k = 0; k < 250; ++k)
            acc += rel_table[r * 250 + k] * W1[(size_t)(1250 + k) * 512 + col];
    } else {
        int r = row - 14;
        int j = r >> 8, v = r & 255;
        int base = 1500 + 85 * j;
        for (int k = 0; k < 85; ++k)
            acc += color_table[v * 85 + k] * W1[(size_t)(base + k) * 512 + col];
    }
    T[(size_t)row * 512 + col] = acc;
}

// ---------------- tiled fp32 GEMM: C[M,N] = A[M,K] @ B[K,N] (+ gathered tables) ----------------
// 64x64 block tile, BK=16, 256 threads, 4x4 micro-tile.

template <bool EMB>
__global__ __launch_bounds__(256) void gemm_kernel(
    const float* __restrict__ A, int lda,
    const float* __restrict__ B, int ldb,
    float* __restrict__ C, int ldc,
    int M, int K,
    const float* __restrict__ T, const int* __restrict__ idx8) {
    __shared__ float As[16][64];
    __shared__ float Bs[16][64];
    int t = threadIdx.x;
    int tr = t >> 4;          // 0..15 (row group)
    int tc = t & 15;          // 0..15 (col group)
    int row0 = blockIdx.x * 64;
    int col0 = blockIdx.y * 64;
    float acc[4][4] = {};

    int ar = t >> 2;          // A load: row 0..63
    int ak = (t & 3) * 4;     //         k  0,4,8,12
    int bkr = t >> 4;         // B load: k 0..15
    int bcc = (t & 15) * 4;   //         col*4

    int ntiles = (K + 15) / 16;
    for (int kt = 0; kt < ntiles; ++kt) {
        int kbase = kt * 16;
        {
            int grow = row0 + ar;
            bool rok = grow < M;
            const float* ap = A + (size_t)grow * lda + kbase + ak;
#pragma unroll
            for (int i = 0; i < 4; ++i) {
                int k = kbase + ak + i;
                As[ak + i][ar] = (rok && k < K) ? ap[i] : 0.0f;
            }
        }
        {
            int k = kbase + bkr;
            float4 v = make_float4(0.f, 0.f, 0.f, 0.f);
            if (k < K) v = *(const float4*)(B + (size_t)k * ldb + col0 + bcc);
            Bs[bkr][bcc + 0] = v.x; Bs[bkr][bcc + 1] = v.y;
            Bs[bkr][bcc + 2] = v.z; Bs[bkr][bcc + 3] = v.w;
        }
        __syncthreads();
#pragma unroll
        for (int k = 0; k < 16; ++k) {
            float a[4], b[4];
#pragma unroll
            for (int i = 0; i < 4; ++i) a[i] = As[k][tr * 4 + i];
#pragma unroll
            for (int j = 0; j < 4; ++j) b[j] = Bs[k][tc * 4 + j];
#pragma unroll
            for (int i = 0; i < 4; ++i)
#pragma unroll
                for (int j = 0; j < 4; ++j)
                    acc[i][j] += a[i] * b[j];
        }
        __syncthreads();
    }

#pragma unroll
    for (int i = 0; i < 4; ++i) {
        int m = row0 + tr * 4 + i;
        if (m >= M) continue;
        float emb[4] = {0.f, 0.f, 0.f, 0.f};
        if (EMB) {
            const int* ix = idx8 + m * 8;
            const float* Tl = T + (size_t)ix[0] * 512;
            const float* Tr = T + (size_t)(3 + ix[1]) * 512;
            const float* T0 = T + (size_t)(14 + ix[2]) * 512;
            const float* T1 = T + (size_t)(14 + 256 + ix[3]) * 512;
            const float* T2 = T + (size_t)(14 + 512 + ix[4]) * 512;
#pragma unroll
            for (int j = 0; j < 4; ++j) {
                int c = col0 + tc * 4 + j;
                emb[j] = Tl[c] + Tr[c] + T0[c] + T1[c] + T2[c];
            }
        }
#pragma unroll
        for (int j = 0; j < 4; ++j) {
            int c = col0 + tc * 4 + j;
            C[(size_t)m * ldc + c] = acc[i][j] + emb[j];
        }
    }
}

// ---------------- aggregation: out = lrelu( sum_in h'[src]*norm + h'[n]*dinv^2 + b ) ----------------

template <int F>
__global__ __launch_bounds__(256) void agg_kernel(
    const float* __restrict__ H, const float* __restrict__ dinv,
    const int* __restrict__ offs, const int* __restrict__ csr_src,
    const float* __restrict__ csr_norm, const float* __restrict__ bias,
    float* __restrict__ out, int n_nodes) {
    constexpr int TPN = F / 4;
    constexpr int NPB = 256 / TPN;
    int n = blockIdx.x * NPB + threadIdx.x / TPN;
    if (n >= n_nodes) return;
    int lane = threadIdx.x % TPN;
    int c = lane * 4;
    float di = dinv[n];
    float s = di * di;
    float4 h = *(const float4*)(H + (size_t)n * F + c);
    float4 acc = make_float4(h.x * s, h.y * s, h.z * s, h.w * s);
    int e0 = offs[n], e1 = offs[n + 1];
    for (int e = e0; e < e1; ++e) {
        int src = csr_src[e];
        float w = csr_norm[e];
        float4 v = *(const float4*)(H + (size_t)src * F + c);
        acc.x += v.x * w; acc.y += v.y * w; acc.z += v.z * w; acc.w += v.w * w;
    }
    float4 b = *(const float4*)(bias + c);
    acc.x += b.x; acc.y += b.y; acc.z += b.z; acc.w += b.w;
    acc.x = acc.x > 0.f ? acc.x : 0.01f * acc.x;
    acc.y = acc.y > 0.f ? acc.y : 0.01f * acc.y;
    acc.z = acc.z > 0.f ? acc.z : 0.01f * acc.z;
    acc.w = acc.w > 0.f ? acc.w : 0.01f * acc.w;
    *(float4*)(out + (size_t)n * F + c) = acc;
}

// ---------------- final projection: out = h3 @ Wp + bp ----------------

__global__ void proj_kernel(const float* __restrict__ H, const float* __restrict__ Wp,
                            const float* __restrict__ bp, float* __restrict__ out, int n_nodes) {
    int t = blockIdx.x * 192 + threadIdx.x;
    int n = t / 3, j = t % 3;
    if (n >= n_nodes) return;
    float acc = bp[j];
    const float* h = H + (size_t)n * 64;
    for (int c = 0; c < 64; ++c) acc += h[c] * Wp[c * 3 + j];
    out[n * 3 + j] = acc;
}

// ---------------- launch ----------------

extern "C" void kernel_launch(void* const* d_in, const int* in_sizes, int n_in,
                              void* d_out, int out_size, void* d_ws, size_t ws_size,
                              hipStream_t stream) {
    const float* x           = (const float*)d_in[0];
    const int*   edge_index  = (const int*)d_in[1];
    const float* edge_attr   = (const float*)d_in[2];
    const float* layer_table = (const float*)d_in[3];
    const float* rel_table   = (const float*)d_in[4];
    const float* color_table = (const float*)d_in[5];
    const float* W1 = (const float*)d_in[6];
    const float* b1 = (const float*)d_in[7];
    const float* W2 = (const float*)d_in[8];
    const float* b2 = (const float*)d_in[9];
    const float* W3 = (const float*)d_in[10];
    const float* b3 = (const float*)d_in[11];
    const float* Wp = (const float*)d_in[12];
    const float* bp = (const float*)d_in[13];
    float* out = (float*)d_out;

    const int N = NNODES, E = NEDGES;

    // workspace carve (16B-aligned chunks, float4-accessed buffers first)
    char* p = (char*)d_ws;
    float* deg      = (float*)p; p += (size_t)N * 4;
    float* dinv     = (float*)p; p += (size_t)N * 4;
    float* T        = (float*)p; p += (size_t)782 * 512 * 4;
    float* csr_norm = (float*)p; p += (size_t)E * 4;
    float* bufA     = (float*)p; p += (size_t)N * 512 * 4;
    float* bufB     = (float*)p; p += (size_t)N * 512 * 4;
    int*   counts   = (int*)p;   p += (size_t)N * 4;
    int*   cursor   = (int*)p;   p += (size_t)N * 4;
    int*   csr_src  = (int*)p;   p += (size_t)E * 4;
    int*   idx8     = (int*)p;   p += (size_t)N * 8 * 4;
    int*   offs     = (int*)p;   p += (size_t)(N + 1) * 4;

    hipMemsetAsync(deg, 0, (size_t)N * 4, stream);
    hipMemsetAsync(counts, 0, (size_t)N * 4, stream);
    hipMemsetAsync(cursor, 0, (size_t)N * 4, stream);

    edge_deg_kernel<<<(E + 255) / 256, 256, 0, stream>>>(edge_index, edge_attr, deg, counts, E);
    dinv_kernel<<<(N + 255) / 256, 256, 0, stream>>>(deg, dinv, N);
    scan_kernel<<<1, 1024, 0, stream>>>(counts, offs, N);
    scatter_kernel<<<(E + 255) / 256, 256, 0, stream>>>(edge_index, edge_attr, dinv, offs,
                                                        cursor, csr_src, csr_norm, E);
    idx_kernel<<<(N + 255) / 256, 256, 0, stream>>>(x, idx8, N);
    tables_kernel<<<(782 * 512 + 255) / 256, 256, 0, stream>>>(layer_table, rel_table,
                                                               color_table, W1, T);

    // layer 1: bufA = resnet @ W1[250:1250] + gathered tables ; bufB = lrelu(agg + b1)
    {
        dim3 grid((N + 63) / 64, 512 / 64);
        gemm_kernel<true><<<grid, 256, 0, stream>>>(x + 1, XW, W1 + 250 * 512, 512,
                                                    bufA, 512, N, 1000, T, idx8);
        agg_kernel<512><<<(N + 1) / 2, 256, 0, stream>>>(bufA, dinv, offs, csr_src, csr_norm,
                                                         b1, bufB, N);
    }
    // layer 2
    {
        dim3 grid((N + 63) / 64, 256 / 64);
        gemm_kernel<false><<<grid, 256, 0, stream>>>(bufB, 512, W2, 256,
                                                     bufA, 256, N, 512, nullptr, nullptr);
        agg_kernel<256><<<(N + 3) / 4, 256, 0, stream>>>(bufA, dinv, offs, csr_src, csr_norm,
                                                         b2, bufB, N);
    }
    // layer 3
    {
        dim3 grid((N + 63) / 64, 1);
        gemm_kernel<false><<<grid, 256, 0, stream>>>(bufB, 256, W3, 64,
                                                     bufA, 64, N, 256, nullptr, nullptr);
        agg_kernel<64><<<(N + 15) / 16, 256, 0, stream>>>(bufA, dinv, offs, csr_src, csr_norm,
                                                          b3, bufB, N);
    }
    // projection
    proj_kernel<<<(N * 3 + 191) / 192, 192, 0, stream>>>(bufB, Wp, bp, out, N);
}

// Round 2
// 749.050 us; speedup vs baseline: 1.3041x; 1.3041x over previous
//
#include <hip/hip_runtime.h>
#include <hip/hip_bf16.h>

#define NNODES 20000
#define NEDGES 320000
#define XW 1005          // x row width: 1 + 1000 + 1 + 3

typedef __attribute__((ext_vector_type(8))) short short8;
typedef __attribute__((ext_vector_type(4))) float f32x4;

// ---------------- CSR build ----------------

__global__ void edge_deg_kernel(const int* __restrict__ ei, const float* __restrict__ ea,
                                float* __restrict__ deg, int* __restrict__ counts, int E) {
    int e = blockIdx.x * 256 + threadIdx.x;
    if (e >= E) return;
    int dst = ei[E + e];
    atomicAdd(&deg[dst], ea[e]);
    atomicAdd(&counts[dst], 1);
}

__global__ void dinv_kernel(const float* __restrict__ deg, float* __restrict__ dinv, int n) {
    int i = blockIdx.x * 256 + threadIdx.x;
    if (i >= n) return;
    float d = deg[i] + 1.0f;
    dinv[i] = 1.0f / sqrtf(d);
}

__global__ __launch_bounds__(1024) void scan_kernel(const int* __restrict__ counts,
                                                    int* __restrict__ offs, int n) {
    __shared__ int sh[1024];
    __shared__ int carry_s;
    int t = threadIdx.x;
    if (t == 0) carry_s = 0;
    __syncthreads();
    for (int base = 0; base < n; base += 1024) {
        int i = base + t;
        int v = (i < n) ? counts[i] : 0;
        sh[t] = v;
        __syncthreads();
        for (int off = 1; off < 1024; off <<= 1) {
            int add = (t >= off) ? sh[t - off] : 0;
            __syncthreads();
            sh[t] += add;
            __syncthreads();
        }
        int carry = carry_s;
        if (i < n) offs[i] = carry + sh[t] - v;   // exclusive
        __syncthreads();
        if (t == 1023) carry_s = carry + sh[1023];
        __syncthreads();
    }
    if (t == 0) offs[n] = carry_s;
}

__global__ void scatter_kernel(const int* __restrict__ ei, const float* __restrict__ ea,
                               const float* __restrict__ dinv, const int* __restrict__ offs,
                               int* __restrict__ cursor, int* __restrict__ csr_src,
                               float* __restrict__ csr_norm, int E) {
    int e = blockIdx.x * 256 + threadIdx.x;
    if (e >= E) return;
    int src = ei[e];
    int dst = ei[E + e];
    int slot = offs[dst] + atomicAdd(&cursor[dst], 1);
    csr_src[slot] = src;
    csr_norm[slot] = dinv[src] * ea[e] * dinv[dst];
}

// ---------------- embedding indices ----------------

__global__ void idx_kernel(const float* __restrict__ x, int* __restrict__ idx8, int n) {
    int i = blockIdx.x * 256 + threadIdx.x;
    if (i >= n) return;
    const float* r = x + (size_t)i * XW;
    idx8[i * 8 + 0] = (int)(r[0] - 1.0f);                       // li in 0..2
    idx8[i * 8 + 1] = (int)rintf(fabsf(r[1001]) * 10.0f);       // ri in 0..10
    idx8[i * 8 + 2] = (int)r[1002];
    idx8[i * 8 + 3] = (int)r[1003];
    idx8[i * 8 + 4] = (int)r[1004];
}

// ---------------- table pre-GEMMs: T is (3 + 11 + 3*256) x 512 ----------------

__global__ __launch_bounds__(256) void tables_kernel(
    const float* __restrict__ layer_table, const float* __restrict__ rel_table,
    const float* __restrict__ color_table, const float* __restrict__ W1,
    float* __restrict__ T) {
    int g = blockIdx.x * 256 + threadIdx.x;
    if (g >= 782 * 512) return;
    int row = g >> 9, col = g & 511;
    float acc = 0.0f;
    if (row < 3) {
        for (int k = 0; k < 250; ++k)
            acc += layer_table[row * 250 + k] * W1[(size_t)k * 512 + col];
    } else if (row < 14) {
        int r = row - 3;
        for (int k = 0; k < 250; ++k)
            acc += rel_table[r * 250 + k] * W1[(size_t)(1250 + k) * 512 + col];
    } else {
        int r = row - 14;
        int j = r >> 8, v = r & 255;
        int base = 1500 + 85 * j;
        for (int k = 0; k < 85; ++k)
            acc += color_table[v * 85 + k] * W1[(size_t)(base + k) * 512 + col];
    }
    T[(size_t)row * 512 + col] = acc;
}

// ---------------- embedding add: H[n][c] += sum of 5 gathered T rows ----------------

__global__ __launch_bounds__(256) void emb_add_kernel(float* __restrict__ H,
                                                      const float* __restrict__ T,
                                                      const int* __restrict__ idx8, int n) {
    int g = blockIdx.x * 256 + threadIdx.x;
    if (g >= n * 128) return;
    int node = g >> 7, c = (g & 127) * 4;
    const int* ix = idx8 + node * 8;
    const float* Tl = T + (size_t)ix[0] * 512 + c;
    const float* Tr = T + (size_t)(3 + ix[1]) * 512 + c;
    const float* T0 = T + (size_t)(14 + ix[2]) * 512 + c;
    const float* T1 = T + (size_t)(14 + 256 + ix[3]) * 512 + c;
    const float* T2 = T + (size_t)(14 + 512 + ix[4]) * 512 + c;
    float* h = H + (size_t)node * 512 + c;
    float4 a = *(float4*)h;
    a.x += Tl[0] + Tr[0] + T0[0] + T1[0] + T2[0];
    a.y += Tl[1] + Tr[1] + T0[1] + T1[1] + T2[1];
    a.z += Tl[2] + Tr[2] + T0[2] + T1[2] + T2[2];
    a.w += Tl[3] + Tr[3] + T0[3] + T1[3] + T2[3];
    *(float4*)h = a;
}

// ---------------- split-bf16 MFMA GEMM: C[M,N] = A[M,K] @ B[K,N] ----------------
// fp32 ~= hi(bf16) + lo(bf16);  A.B ~= Ah.Bh + Ah.Bl + Al.Bh  (error ~2^-16 rel)
// 128x64 block tile, BK=32, 256 threads = 4 waves in 2x2; wave computes 64x32
// via 4x2 grid of 16x16x32 MFMA tiles.
// LDS row stride 40 ushorts (80 B): fragment ds_read_b128 -> 2-way banks (free).

__device__ inline void cvt2(float v0, float v1, unsigned& h, unsigned& l) {
    unsigned u0 = __float_as_uint(v0), u1 = __float_as_uint(v1);
    float h0 = __uint_as_float(u0 & 0xffff0000u);
    float h1 = __uint_as_float(u1 & 0xffff0000u);
    h = (u0 >> 16) | (u1 & 0xffff0000u);
    float l0 = v0 - h0, l1 = v1 - h1;
    l = (__float_as_uint(l0) >> 16) | (__float_as_uint(l1) & 0xffff0000u);
}

__global__ __launch_bounds__(256) void gemm_mfma_kernel(
    const float* __restrict__ A, int lda,
    const float* __restrict__ B, int ldb,
    float* __restrict__ C, int ldc,
    int M, int K) {
    __shared__ unsigned short Ah[128 * 40];
    __shared__ unsigned short Al[128 * 40];
    __shared__ unsigned short Bh[64 * 40];
    __shared__ unsigned short Bl[64 * 40];

    const int t = threadIdx.x;
    const int row0 = blockIdx.y * 128;
    const int col0 = blockIdx.x * 64;

    const int lane = t & 63;
    const int w = t >> 6;
    const int wr = w >> 1, wc = w & 1;
    const int l15 = lane & 15, quad = lane >> 4;

    // A staging: 8 threads per row-segment of 4 k's; 4 row-blocks of 32
    const int ar = t >> 3;          // 0..31
    const int ak = (t & 7) * 4;     // 0,4,...,28
    // B staging: lane n = t&63, wave w covers k-block of 8
    const int bn = t & 63;
    const int bk0 = (t >> 6) * 8;

    f32x4 acc[4][2];
#pragma unroll
    for (int i = 0; i < 4; ++i)
#pragma unroll
        for (int j = 0; j < 2; ++j)
            acc[i][j] = (f32x4){0.f, 0.f, 0.f, 0.f};

    const int ntiles = (K + 31) / 32;
    for (int kt = 0; kt < ntiles; ++kt) {
        const int kbase = kt * 32;
        // ---- stage A (128x32 fp32 -> hi/lo bf16) ----
#pragma unroll
        for (int rb = 0; rb < 4; ++rb) {
            int r = rb * 32 + ar;
            int grow = row0 + r;
            bool rok = grow < M;
            const float* ap = A + (size_t)grow * lda + kbase + ak;
            float v[4];
#pragma unroll
            for (int i = 0; i < 4; ++i) {
                int k = kbase + ak + i;
                v[i] = (rok && k < K) ? ap[i] : 0.0f;
            }
            unsigned h01, l01, h23, l23;
            cvt2(v[0], v[1], h01, l01);
            cvt2(v[2], v[3], h23, l23);
            unsigned* ph = (unsigned*)&Ah[r * 40 + ak];
            unsigned* pl = (unsigned*)&Al[r * 40 + ak];
            ph[0] = h01; ph[1] = h23;
            pl[0] = l01; pl[1] = l23;
        }
        // ---- stage B (32x64 fp32 -> hi/lo bf16, transposed to [n][k]) ----
        {
            float v[8];
#pragma unroll
            for (int j = 0; j < 8; ++j) {
                int k = kbase + bk0 + j;
                v[j] = (k < K) ? B[(size_t)k * ldb + col0 + bn] : 0.0f;
            }
            unsigned* ph = (unsigned*)&Bh[bn * 40 + bk0];
            unsigned* pl = (unsigned*)&Bl[bn * 40 + bk0];
#pragma unroll
            for (int j = 0; j < 4; ++j) {
                unsigned h, l;
                cvt2(v[2 * j], v[2 * j + 1], h, l);
                ph[j] = h; pl[j] = l;
            }
        }
        __syncthreads();
        // ---- fragments + MFMA ----
        short8 fah[4], fal[4], fbh[2], fbl[2];
#pragma unroll
        for (int mt = 0; mt < 4; ++mt) {
            int off = (wr * 64 + mt * 16 + l15) * 40 + quad * 8;
            fah[mt] = *(const short8*)&Ah[off];
            fal[mt] = *(const short8*)&Al[off];
        }
#pragma unroll
        for (int nt = 0; nt < 2; ++nt) {
            int off = (wc * 32 + nt * 16 + l15) * 40 + quad * 8;
            fbh[nt] = *(const short8*)&Bh[off];
            fbl[nt] = *(const short8*)&Bl[off];
        }
#pragma unroll
        for (int mt = 0; mt < 4; ++mt)
#pragma unroll
            for (int nt = 0; nt < 2; ++nt) {
                acc[mt][nt] = __builtin_amdgcn_mfma_f32_16x16x32_bf16(fah[mt], fbh[nt], acc[mt][nt], 0, 0, 0);
                acc[mt][nt] = __builtin_amdgcn_mfma_f32_16x16x32_bf16(fah[mt], fbl[nt], acc[mt][nt], 0, 0, 0);
                acc[mt][nt] = __builtin_amdgcn_mfma_f32_16x16x32_bf16(fal[mt], fbh[nt], acc[mt][nt], 0, 0, 0);
            }
        __syncthreads();
    }

    // ---- store: C/D layout col=lane&15, row=quad*4+r ----
#pragma unroll
    for (int mt = 0; mt < 4; ++mt)
#pragma unroll
        for (int nt = 0; nt < 2; ++nt)
#pragma unroll
            for (int r = 0; r < 4; ++r) {
                int row = row0 + wr * 64 + mt * 16 + quad * 4 + r;
                if (row < M)
                    C[(size_t)row * ldc + col0 + wc * 32 + nt * 16 + l15] = acc[mt][nt][r];
            }
}

// ---------------- aggregation: out = lrelu( sum_in h'[src]*norm + h'[n]*dinv^2 + b ) ----------------

template <int F>
__global__ __launch_bounds__(256) void agg_kernel(
    const float* __restrict__ H, const float* __restrict__ dinv,
    const int* __restrict__ offs, const int* __restrict__ csr_src,
    const float* __restrict__ csr_norm, const float* __restrict__ bias,
    float* __restrict__ out, int n_nodes) {
    constexpr int TPN = F / 4;
    constexpr int NPB = 256 / TPN;
    int n = blockIdx.x * NPB + threadIdx.x / TPN;
    if (n >= n_nodes) return;
    int lane = threadIdx.x % TPN;
    int c = lane * 4;
    float di = dinv[n];
    float s = di * di;
    float4 h = *(const float4*)(H + (size_t)n * F + c);
    float4 acc = make_float4(h.x * s, h.y * s, h.z * s, h.w * s);
    int e0 = offs[n], e1 = offs[n + 1];
    for (int e = e0; e < e1; ++e) {
        int src = csr_src[e];
        float w = csr_norm[e];
        float4 v = *(const float4*)(H + (size_t)src * F + c);
        acc.x += v.x * w; acc.y += v.y * w; acc.z += v.z * w; acc.w += v.w * w;
    }
    float4 b = *(const float4*)(bias + c);
    acc.x += b.x; acc.y += b.y; acc.z += b.z; acc.w += b.w;
    acc.x = acc.x > 0.f ? acc.x : 0.01f * acc.x;
    acc.y = acc.y > 0.f ? acc.y : 0.01f * acc.y;
    acc.z = acc.z > 0.f ? acc.z : 0.01f * acc.z;
    acc.w = acc.w > 0.f ? acc.w : 0.01f * acc.w;
    *(float4*)(out + (size_t)n * F + c) = acc;
}

// ---------------- final projection: out = h3 @ Wp + bp ----------------

__global__ void proj_kernel(const float* __restrict__ H, const float* __restrict__ Wp,
                            const float* __restrict__ bp, float* __restrict__ out, int n_nodes) {
    int t = blockIdx.x * 192 + threadIdx.x;
    int n = t / 3, j = t % 3;
    if (n >= n_nodes) return;
    float acc = bp[j];
    const float* h = H + (size_t)n * 64;
    for (int c = 0; c < 64; ++c) acc += h[c] * Wp[c * 3 + j];
    out[n * 3 + j] = acc;
}

// ---------------- launch ----------------

extern "C" void kernel_launch(void* const* d_in, const int* in_sizes, int n_in,
                              void* d_out, int out_size, void* d_ws, size_t ws_size,
                              hipStream_t stream) {
    const float* x           = (const float*)d_in[0];
    const int*   edge_index  = (const int*)d_in[1];
    const float* edge_attr   = (const float*)d_in[2];
    const float* layer_table = (const float*)d_in[3];
    const float* rel_table   = (const float*)d_in[4];
    const float* color_table = (const float*)d_in[5];
    const float* W1 = (const float*)d_in[6];
    const float* b1 = (const float*)d_in[7];
    const float* W2 = (const float*)d_in[8];
    const float* b2 = (const float*)d_in[9];
    const float* W3 = (const float*)d_in[10];
    const float* b3 = (const float*)d_in[11];
    const float* Wp = (const float*)d_in[12];
    const float* bp = (const float*)d_in[13];
    float* out = (float*)d_out;

    const int N = NNODES, E = NEDGES;

    char* p = (char*)d_ws;
    float* deg      = (float*)p; p += (size_t)N * 4;
    float* dinv     = (float*)p; p += (size_t)N * 4;
    float* T        = (float*)p; p += (size_t)782 * 512 * 4;
    float* csr_norm = (float*)p; p += (size_t)E * 4;
    float* bufA     = (float*)p; p += (size_t)N * 512 * 4;
    float* bufB     = (float*)p; p += (size_t)N * 512 * 4;
    int*   counts   = (int*)p;   p += (size_t)N * 4;
    int*   cursor   = (int*)p;   p += (size_t)N * 4;
    int*   csr_src  = (int*)p;   p += (size_t)E * 4;
    int*   idx8     = (int*)p;   p += (size_t)N * 8 * 4;
    int*   offs     = (int*)p;   p += (size_t)(N + 1) * 4;

    hipMemsetAsync(deg, 0, (size_t)N * 4, stream);
    hipMemsetAsync(counts, 0, (size_t)N * 4, stream);
    hipMemsetAsync(cursor, 0, (size_t)N * 4, stream);

    edge_deg_kernel<<<(E + 255) / 256, 256, 0, stream>>>(edge_index, edge_attr, deg, counts, E);
    dinv_kernel<<<(N + 255) / 256, 256, 0, stream>>>(deg, dinv, N);
    scan_kernel<<<1, 1024, 0, stream>>>(counts, offs, N);
    scatter_kernel<<<(E + 255) / 256, 256, 0, stream>>>(edge_index, edge_attr, dinv, offs,
                                                        cursor, csr_src, csr_norm, E);
    idx_kernel<<<(N + 255) / 256, 256, 0, stream>>>(x, idx8, N);
    tables_kernel<<<(782 * 512 + 255) / 256, 256, 0, stream>>>(layer_table, rel_table,
                                                               color_table, W1, T);

    const int nrb = (N + 127) / 128;   // 157 row-bands

    // layer 1: bufA = resnet @ W1[250:1250]; += gathered tables; bufB = lrelu(agg + b1)
    {
        dim3 grid(512 / 64, nrb);
        gemm_mfma_kernel<<<grid, 256, 0, stream>>>(x + 1, XW, W1 + 250 * 512, 512,
                                                   bufA, 512, N, 1000);
        emb_add_kernel<<<(N * 128 + 255) / 256, 256, 0, stream>>>(bufA, T, idx8, N);
        agg_kernel<512><<<(N + 1) / 2, 256, 0, stream>>>(bufA, dinv, offs, csr_src, csr_norm,
                                                         b1, bufB, N);
    }
    // layer 2
    {
        dim3 grid(256 / 64, nrb);
        gemm_mfma_kernel<<<grid, 256, 0, stream>>>(bufB, 512, W2, 256,
                                                   bufA, 256, N, 512);
        agg_kernel<256><<<(N + 3) / 4, 256, 0, stream>>>(bufA, dinv, offs, csr_src, csr_norm,
                                                         b2, bufB, N);
    }
    // layer 3
    {
        dim3 grid(64 / 64, nrb);
        gemm_mfma_kernel<<<grid, 256, 0, stream>>>(bufB, 256, W3, 64,
                                                   bufA, 64, N, 256);
        agg_kernel<64><<<(N + 15) / 16, 256, 0, stream>>>(bufA, dinv, offs, csr_src, csr_norm,
                                                          b3, bufB, N);
    }
    // projection
    proj_kernel<<<(N * 3 + 191) / 192, 192, 0, stream>>>(bufB, Wp, bp, out, N);
}

// Round 3
// 564.323 us; speedup vs baseline: 1.7310x; 1.3273x over previous
//
#include <hip/hip_runtime.h>
#include <hip/hip_bf16.h>

#define NNODES 20000
#define NEDGES 320000
#define XW 1005          // x row width: 1 + 1000 + 1 + 3
#define MP 20096         // 157 * 128 row-padded M

typedef __attribute__((ext_vector_type(8))) short short8;
typedef __attribute__((ext_vector_type(4))) float f32x4;
typedef __attribute__((ext_vector_type(4))) unsigned short u16x4;

typedef const __attribute__((address_space(1))) unsigned int gas_u32;
typedef __attribute__((address_space(3))) unsigned int las_u32;

__device__ inline void ld16(const unsigned short* g, unsigned short* l) {
    __builtin_amdgcn_global_load_lds((gas_u32*)g, (las_u32*)l, 16, 0, 0);
}

__device__ inline void split1(float v, unsigned short& h, unsigned short& l) {
    unsigned u = __float_as_uint(v);
    h = (unsigned short)(u >> 16);
    float hf = __uint_as_float(u & 0xffff0000u);
    l = (unsigned short)(__float_as_uint(v - hf) >> 16);
}

// ---------------- CSR build ----------------

__global__ void edge_deg_kernel(const int* __restrict__ ei, const float* __restrict__ ea,
                                float* __restrict__ deg, int* __restrict__ counts, int E) {
    int e = blockIdx.x * 256 + threadIdx.x;
    if (e >= E) return;
    int dst = ei[E + e];
    atomicAdd(&deg[dst], ea[e]);
    atomicAdd(&counts[dst], 1);
}

__global__ void dinv_kernel(const float* __restrict__ deg, float* __restrict__ dinv, int n) {
    int i = blockIdx.x * 256 + threadIdx.x;
    if (i >= n) return;
    float d = deg[i] + 1.0f;
    dinv[i] = 1.0f / sqrtf(d);
}

__global__ __launch_bounds__(1024) void scan_kernel(const int* __restrict__ counts,
                                                    int* __restrict__ offs, int n) {
    __shared__ int wsum[16];
    __shared__ int wpre[16];
    __shared__ int carry_s;
    int t = threadIdx.x;
    int lane = t & 63, wid = t >> 6;
    if (t == 0) carry_s = 0;
    __syncthreads();
    for (int base = 0; base < n; base += 1024) {
        int i = base + t;
        int v = (i < n) ? counts[i] : 0;
        int x = v;
#pragma unroll
        for (int d = 1; d < 64; d <<= 1) {
            int u = __shfl_up(x, d, 64);
            if (lane >= d) x += u;
        }
        if (lane == 63) wsum[wid] = x;
        __syncthreads();
        if (wid == 0) {
            int s = (lane < 16) ? wsum[lane] : 0;
#pragma unroll
            for (int d = 1; d < 16; d <<= 1) {
                int u = __shfl_up(s, d, 64);
                if (lane >= d) s += u;
            }
            if (lane < 16) wpre[lane] = s;
        }
        __syncthreads();
        int carry = carry_s;
        int prefix = carry + (wid > 0 ? wpre[wid - 1] : 0);
        if (i < n) offs[i] = prefix + x - v;   // exclusive
        __syncthreads();
        if (t == 1023) carry_s = prefix + x;
    }
    __syncthreads();
    if (t == 0) offs[n] = carry_s;
}

__global__ void scatter_kernel(const int* __restrict__ ei, const float* __restrict__ ea,
                               const float* __restrict__ dinv, const int* __restrict__ offs,
                               int* __restrict__ cursor, int* __restrict__ csr_src,
                               float* __restrict__ csr_norm, int E) {
    int e = blockIdx.x * 256 + threadIdx.x;
    if (e >= E) return;
    int src = ei[e];
    int dst = ei[E + e];
    int slot = offs[dst] + atomicAdd(&cursor[dst], 1);
    csr_src[slot] = src;
    csr_norm[slot] = dinv[src] * ea[e] * dinv[dst];
}

// ---------------- embedding indices ----------------

__global__ void idx_kernel(const float* __restrict__ x, int* __restrict__ idx8, int n) {
    int i = blockIdx.x * 256 + threadIdx.x;
    if (i >= n) return;
    const float* r = x + (size_t)i * XW;
    idx8[i * 8 + 0] = (int)(r[0] - 1.0f);
    idx8[i * 8 + 1] = (int)rintf(fabsf(r[1001]) * 10.0f);
    idx8[i * 8 + 2] = (int)r[1002];
    idx8[i * 8 + 3] = (int)r[1003];
    idx8[i * 8 + 4] = (int)r[1004];
}

// ---------------- table pre-GEMMs: T is (3 + 11 + 3*256) x 512 ----------------

__global__ __launch_bounds__(256) void tables_kernel(
    const float* __restrict__ layer_table, const float* __restrict__ rel_table,
    const float* __restrict__ color_table, const float* __restrict__ W1,
    float* __restrict__ T) {
    int g = blockIdx.x * 256 + threadIdx.x;
    if (g >= 782 * 512) return;
    int row = g >> 9, col = g & 511;
    float acc = 0.0f;
    if (row < 3) {
        for (int k = 0; k < 250; ++k)
            acc += layer_table[row * 250 + k] * W1[(size_t)k * 512 + col];
    } else if (row < 14) {
        int r = row - 3;
        for (int k = 0; k < 250; ++k)
            acc += rel_table[r * 250 + k] * W1[(size_t)(1250 + k) * 512 + col];
    } else {
        int r = row - 14;
        int j = r >> 8, v = r & 255;
        int base = 1500 + 85 * j;
        for (int k = 0; k < 85; ++k)
            acc += color_table[v * 85 + k] * W1[(size_t)(base + k) * 512 + col];
    }
    T[(size_t)row * 512 + col] = acc;
}

// ---------------- operand pre-split ----------------

// A1: x[:,1:1001] -> hi/lo bf16, [20000][1024] (k-pad zeroed)
__global__ __launch_bounds__(256) void a1_split_kernel(const float* __restrict__ x,
                                                       unsigned short* __restrict__ Ah,
                                                       unsigned short* __restrict__ Al) {
    int g = blockIdx.x * 256 + threadIdx.x;
    if (g >= NNODES * 256) return;
    int row = g >> 8, c4 = (g & 255) << 2;
    const float* xp = x + (size_t)row * XW + 1 + c4;
    u16x4 h, l;
#pragma unroll
    for (int i = 0; i < 4; ++i) {
        float v = (c4 + i < 1000) ? xp[i] : 0.0f;
        unsigned short hh, ll;
        split1(v, hh, ll);
        h[i] = (short)hh; l[i] = (short)ll;
    }
    *(u16x4*)&Ah[(size_t)row * 1024 + c4] = h;
    *(u16x4*)&Al[(size_t)row * 1024 + c4] = l;
}

// Bt: W[K][Ncols] (row offset koff) -> transposed hi/lo bf16 [Ncols][Kp]
__global__ __launch_bounds__(256) void bt_split_kernel(const float* __restrict__ W, int ldw,
                                                       int koff, int K, int Kp, int Ncols,
                                                       unsigned short* __restrict__ Bh,
                                                       unsigned short* __restrict__ Bl) {
    int g = blockIdx.x * 256 + threadIdx.x;
    int kp4 = Kp >> 2;
    if (g >= Ncols * kp4) return;
    int n = g / kp4, c4 = (g % kp4) << 2;
    u16x4 h, l;
#pragma unroll
    for (int i = 0; i < 4; ++i) {
        int k = c4 + i;
        float v = (k < K) ? W[(size_t)(koff + k) * ldw + n] : 0.0f;
        unsigned short hh, ll;
        split1(v, hh, ll);
        h[i] = (short)hh; l[i] = (short)ll;
    }
    *(u16x4*)&Bh[(size_t)n * Kp + c4] = h;
    *(u16x4*)&Bl[(size_t)n * Kp + c4] = l;
}

// ---------------- split-bf16 MFMA GEMM, async-LDS staging ----------------
// C[M,N] = (Ah+Al)[M,Kp] @ (Bh+Bl)^T[Kp,N], 3-pass (hh+hl+lh).
// BM=128, BN in {128,64}, BK=32. 256 thr = 4 waves (2x2); wave = 64 x BN/2.
// LDS rows 64 B, k-chunks (16 B) XOR-swizzled by (row>>1)&3 so fragment
// ds_read_b128 is 2-way bank aliased (free) without padding (global_load_lds
// requires contiguous lane deposits).

template <int BN, bool EMB>
__global__ __launch_bounds__(256, 3) void gemm_split_kernel(
    const unsigned short* __restrict__ Ah, const unsigned short* __restrict__ Al, int Kp,
    const unsigned short* __restrict__ Bh, const unsigned short* __restrict__ Bl,
    float* __restrict__ C, int ldc, int M,
    const float* __restrict__ T, const int* __restrict__ idx8) {
    constexpr int NT = BN / 32;     // n-tiles per wave
    constexpr int BJ = BN / 64;     // B staging instrs per wave per plane
    __shared__ __align__(16) unsigned short sAh[128 * 32];
    __shared__ __align__(16) unsigned short sAl[128 * 32];
    __shared__ __align__(16) unsigned short sBh[BN * 32];
    __shared__ __align__(16) unsigned short sBl[BN * 32];

    const int t = threadIdx.x;
    const int lane = t & 63;
    const int w = t >> 6;
    const int wr = w >> 1, wc = w & 1;
    const int l15 = lane & 15, quad = lane >> 4;
    const int row0 = blockIdx.y * 128;
    const int col0 = blockIdx.x * BN;

    const int si_r = lane >> 2;                      // row within 16-row group
    const int si_s = lane & 3;                       // LDS chunk slot
    const int schunk = si_s ^ ((si_r >> 1) & 3);     // global chunk staged into slot
    const int sw = (quad ^ ((l15 >> 1) & 3)) * 8;    // fragment slot offset (ushorts)

    // staging pointers
    const unsigned short* gAh[2]; const unsigned short* gAl[2];
    unsigned short* dAh[2]; unsigned short* dAl[2];
#pragma unroll
    for (int j = 0; j < 2; ++j) {
        int ra = w * 32 + j * 16 + si_r;
        size_t e = (size_t)(row0 + ra) * Kp + schunk * 8;
        gAh[j] = Ah + e; gAl[j] = Al + e;
        dAh[j] = &sAh[(w * 32 + j * 16) * 32];
        dAl[j] = &sAl[(w * 32 + j * 16) * 32];
    }
    const unsigned short* gBh[BJ]; const unsigned short* gBl[BJ];
    unsigned short* dBh[BJ]; unsigned short* dBl[BJ];
#pragma unroll
    for (int j = 0; j < BJ; ++j) {
        int rb = w * (BN / 4) + j * 16 + si_r;
        size_t e = (size_t)(col0 + rb) * Kp + schunk * 8;
        gBh[j] = Bh + e; gBl[j] = Bl + e;
        dBh[j] = &sBh[(w * (BN / 4) + j * 16) * 32];
        dBl[j] = &sBl[(w * (BN / 4) + j * 16) * 32];
    }

    f32x4 acc[4][NT];
#pragma unroll
    for (int i = 0; i < 4; ++i)
#pragma unroll
        for (int j = 0; j < NT; ++j)
            acc[i][j] = (f32x4){0.f, 0.f, 0.f, 0.f};

    for (int kb = 0; kb < Kp; kb += 32) {
#pragma unroll
        for (int j = 0; j < 2; ++j) {
            ld16(gAh[j] + kb, dAh[j]);
            ld16(gAl[j] + kb, dAl[j]);
        }
#pragma unroll
        for (int j = 0; j < BJ; ++j) {
            ld16(gBh[j] + kb, dBh[j]);
            ld16(gBl[j] + kb, dBl[j]);
        }
        __syncthreads();

        short8 fah[4], fal[4], fbh[NT], fbl[NT];
#pragma unroll
        for (int mt = 0; mt < 4; ++mt) {
            int off = (wr * 64 + mt * 16 + l15) * 32 + sw;
            fah[mt] = *(const short8*)&sAh[off];
            fal[mt] = *(const short8*)&sAl[off];
        }
#pragma unroll
        for (int nt = 0; nt < NT; ++nt) {
            int off = (wc * (BN / 2) + nt * 16 + l15) * 32 + sw;
            fbh[nt] = *(const short8*)&sBh[off];
            fbl[nt] = *(const short8*)&sBl[off];
        }
#pragma unroll
        for (int mt = 0; mt < 4; ++mt)
#pragma unroll
            for (int nt = 0; nt < NT; ++nt)
                acc[mt][nt] = __builtin_amdgcn_mfma_f32_16x16x32_bf16(fah[mt], fbh[nt], acc[mt][nt], 0, 0, 0);
#pragma unroll
        for (int mt = 0; mt < 4; ++mt)
#pragma unroll
            for (int nt = 0; nt < NT; ++nt)
                acc[mt][nt] = __builtin_amdgcn_mfma_f32_16x16x32_bf16(fah[mt], fbl[nt], acc[mt][nt], 0, 0, 0);
#pragma unroll
        for (int mt = 0; mt < 4; ++mt)
#pragma unroll
            for (int nt = 0; nt < NT; ++nt)
                acc[mt][nt] = __builtin_amdgcn_mfma_f32_16x16x32_bf16(fal[mt], fbh[nt], acc[mt][nt], 0, 0, 0);
        __syncthreads();
    }

    // epilogue: C/D layout col=lane&15, row=quad*4+r  (+ fused embedding add)
#pragma unroll
    for (int mt = 0; mt < 4; ++mt)
#pragma unroll
        for (int r = 0; r < 4; ++r) {
            int row = row0 + wr * 64 + mt * 16 + quad * 4 + r;
            if (row >= M) continue;
            if (EMB) {
                const int* ix = idx8 + row * 8;
                const float* t0 = T + (size_t)ix[0] * 512;
                const float* t1 = T + (size_t)(3 + ix[1]) * 512;
                const float* t2 = T + (size_t)(14 + ix[2]) * 512;
                const float* t3 = T + (size_t)(270 + ix[3]) * 512;
                const float* t4 = T + (size_t)(526 + ix[4]) * 512;
#pragma unroll
                for (int nt = 0; nt < NT; ++nt) {
                    int col = col0 + wc * (BN / 2) + nt * 16 + l15;
                    float e = t0[col] + t1[col] + t2[col] + t3[col] + t4[col];
                    C[(size_t)row * ldc + col] = acc[mt][nt][r] + e;
                }
            } else {
#pragma unroll
                for (int nt = 0; nt < NT; ++nt) {
                    int col = col0 + wc * (BN / 2) + nt * 16 + l15;
                    C[(size_t)row * ldc + col] = acc[mt][nt][r];
                }
            }
        }
}

// ---------------- aggregation: lrelu( sum_in h'[src]*norm + h'[n]*dinv^2 + b ) ----------------
// SPLIT=true writes hi/lo bf16 planes (next layer's A); else fp32.

template <int F, bool SPLIT>
__global__ __launch_bounds__(256) void agg_kernel(
    const float* __restrict__ H, const float* __restrict__ dinv,
    const int* __restrict__ offs, const int* __restrict__ csr_src,
    const float* __restrict__ csr_norm, const float* __restrict__ bias,
    float* __restrict__ outf, unsigned short* __restrict__ Hh,
    unsigned short* __restrict__ Hl, int n_nodes) {
    constexpr int TPN = F / 4;
    constexpr int NPB = 256 / TPN;
    int n = blockIdx.x * NPB + threadIdx.x / TPN;
    if (n >= n_nodes) return;
    int lane = threadIdx.x % TPN;
    int c = lane * 4;
    float di = dinv[n];
    float s = di * di;
    float4 h = *(const float4*)(H + (size_t)n * F + c);
    float4 acc = make_float4(h.x * s, h.y * s, h.z * s, h.w * s);
    int e0 = offs[n], e1 = offs[n + 1];
    for (int e = e0; e < e1; ++e) {
        int src = csr_src[e];
        float w = csr_norm[e];
        float4 v = *(const float4*)(H + (size_t)src * F + c);
        acc.x += v.x * w; acc.y += v.y * w; acc.z += v.z * w; acc.w += v.w * w;
    }
    float4 b = *(const float4*)(bias + c);
    acc.x += b.x; acc.y += b.y; acc.z += b.z; acc.w += b.w;
    acc.x = acc.x > 0.f ? acc.x : 0.01f * acc.x;
    acc.y = acc.y > 0.f ? acc.y : 0.01f * acc.y;
    acc.z = acc.z > 0.f ? acc.z : 0.01f * acc.z;
    acc.w = acc.w > 0.f ? acc.w : 0.01f * acc.w;
    if (SPLIT) {
        u16x4 hh, ll;
        unsigned short a, bb;
        split1(acc.x, a, bb); hh[0] = (short)a; ll[0] = (short)bb;
        split1(acc.y, a, bb); hh[1] = (short)a; ll[1] = (short)bb;
        split1(acc.z, a, bb); hh[2] = (short)a; ll[2] = (short)bb;
        split1(acc.w, a, bb); hh[3] = (short)a; ll[3] = (short)bb;
        *(u16x4*)(Hh + (size_t)n * F + c) = hh;
        *(u16x4*)(Hl + (size_t)n * F + c) = ll;
    } else {
        *(float4*)(outf + (size_t)n * F + c) = acc;
    }
}

// ---------------- final projection: out = h3 @ Wp + bp ----------------

__global__ void proj_kernel(const float* __restrict__ H, const float* __restrict__ Wp,
                            const float* __restrict__ bp, float* __restrict__ out, int n_nodes) {
    int t = blockIdx.x * 192 + threadIdx.x;
    int n = t / 3, j = t % 3;
    if (n >= n_nodes) return;
    float acc = bp[j];
    const float* h = H + (size_t)n * 64;
    for (int c = 0; c < 64; ++c) acc += h[c] * Wp[c * 3 + j];
    out[n * 3 + j] = acc;
}

// ---------------- launch ----------------

static inline size_t aln(size_t v) { return (v + 255) & ~(size_t)255; }

extern "C" void kernel_launch(void* const* d_in, const int* in_sizes, int n_in,
                              void* d_out, int out_size, void* d_ws, size_t ws_size,
                              hipStream_t stream) {
    const float* x           = (const float*)d_in[0];
    const int*   edge_index  = (const int*)d_in[1];
    const float* edge_attr   = (const float*)d_in[2];
    const float* layer_table = (const float*)d_in[3];
    const float* rel_table   = (const float*)d_in[4];
    const float* color_table = (const float*)d_in[5];
    const float* W1 = (const float*)d_in[6];
    const float* b1 = (const float*)d_in[7];
    const float* W2 = (const float*)d_in[8];
    const float* b2 = (const float*)d_in[9];
    const float* W3 = (const float*)d_in[10];
    const float* b3 = (const float*)d_in[11];
    const float* Wp = (const float*)d_in[12];
    const float* bp = (const float*)d_in[13];
    float* out = (float*)d_out;

    const int N = NNODES, E = NEDGES;

    char* p = (char*)d_ws;
    float* deg      = (float*)p; p += aln((size_t)N * 4);
    float* dinv     = (float*)p; p += aln((size_t)N * 4);
    float* T        = (float*)p; p += aln((size_t)782 * 512 * 4);
    float* csr_norm = (float*)p; p += aln((size_t)E * 4);
    float* C        = (float*)p; p += aln((size_t)MP * 512 * 4);
    unsigned short* BIG = (unsigned short*)p; p += aln((size_t)MP * 2048 * 2);
    unsigned short* Bt1h = (unsigned short*)p; p += aln((size_t)512 * 1024 * 2);
    unsigned short* Bt1l = (unsigned short*)p; p += aln((size_t)512 * 1024 * 2);
    unsigned short* Bt2h = (unsigned short*)p; p += aln((size_t)256 * 512 * 2);
    unsigned short* Bt2l = (unsigned short*)p; p += aln((size_t)256 * 512 * 2);
    unsigned short* Bt3h = (unsigned short*)p; p += aln((size_t)64 * 256 * 2);
    unsigned short* Bt3l = (unsigned short*)p; p += aln((size_t)64 * 256 * 2);
    int*   counts   = (int*)p;   p += aln((size_t)N * 4);
    int*   cursor   = (int*)p;   p += aln((size_t)N * 4);
    int*   csr_src  = (int*)p;   p += aln((size_t)E * 4);
    int*   idx8     = (int*)p;   p += aln((size_t)N * 8 * 4);
    int*   offs     = (int*)p;   p += aln((size_t)(N + 1) * 4);

    // BIG region overlays (temporal reuse):
    unsigned short* A1h = BIG;                          // [MP][1024], live: gemm1
    unsigned short* A1l = BIG + (size_t)MP * 1024;
    unsigned short* H2h = BIG;                          // [MP][512], written after gemm1
    unsigned short* H2l = BIG + (size_t)MP * 512;
    unsigned short* H3h = BIG + (size_t)MP * 1024;      // [MP][256], written after gemm2
    unsigned short* H3l = BIG + (size_t)MP * 1024 + (size_t)MP * 256;
    float*          H4  = (float*)(BIG + (size_t)MP * 1536);  // [N][64] fp32

    hipMemsetAsync(deg, 0, (size_t)N * 4, stream);
    hipMemsetAsync(counts, 0, (size_t)N * 4, stream);
    hipMemsetAsync(cursor, 0, (size_t)N * 4, stream);

    edge_deg_kernel<<<(E + 255) / 256, 256, 0, stream>>>(edge_index, edge_attr, deg, counts, E);
    dinv_kernel<<<(N + 255) / 256, 256, 0, stream>>>(deg, dinv, N);
    scan_kernel<<<1, 1024, 0, stream>>>(counts, offs, N);
    scatter_kernel<<<(E + 255) / 256, 256, 0, stream>>>(edge_index, edge_attr, dinv, offs,
                                                        cursor, csr_src, csr_norm, E);
    idx_kernel<<<(N + 255) / 256, 256, 0, stream>>>(x, idx8, N);
    tables_kernel<<<(782 * 512 + 255) / 256, 256, 0, stream>>>(layer_table, rel_table,
                                                               color_table, W1, T);
    a1_split_kernel<<<(NNODES * 256) / 256, 256, 0, stream>>>(x, A1h, A1l);
    bt_split_kernel<<<(512 * 256 + 255) / 256, 256, 0, stream>>>(W1, 512, 250, 1000, 1024, 512, Bt1h, Bt1l);
    bt_split_kernel<<<(256 * 128 + 255) / 256, 256, 0, stream>>>(W2, 256, 0, 512, 512, 256, Bt2h, Bt2l);
    bt_split_kernel<<<(64 * 64 + 255) / 256, 256, 0, stream>>>(W3, 64, 0, 256, 256, 64, Bt3h, Bt3l);

    const int nrb = MP / 128;   // 157

    // layer 1
    {
        dim3 grid(512 / 128, nrb);
        gemm_split_kernel<128, true><<<grid, 256, 0, stream>>>(A1h, A1l, 1024, Bt1h, Bt1l,
                                                               C, 512, N, T, idx8);
        agg_kernel<512, true><<<(N + 1) / 2, 256, 0, stream>>>(C, dinv, offs, csr_src, csr_norm,
                                                               b1, nullptr, H2h, H2l, N);
    }
    // layer 2
    {
        dim3 grid(256 / 128, nrb);
        gemm_split_kernel<128, false><<<grid, 256, 0, stream>>>(H2h, H2l, 512, Bt2h, Bt2l,
                                                                C, 256, N, nullptr, nullptr);
        agg_kernel<256, true><<<(N + 3) / 4, 256, 0, stream>>>(C, dinv, offs, csr_src, csr_norm,
                                                               b2, nullptr, H3h, H3l, N);
    }
    // layer 3
    {
        dim3 grid(1, nrb);
        gemm_split_kernel<64, false><<<grid, 256, 0, stream>>>(H3h, H3l, 256, Bt3h, Bt3l,
                                                               C, 64, N, nullptr, nullptr);
        agg_kernel<64, false><<<(N + 15) / 16, 256, 0, stream>>>(C, dinv, offs, csr_src, csr_norm,
                                                                 b3, H4, nullptr, nullptr, N);
    }
    // projection
    proj_kernel<<<(N * 3 + 191) / 192, 192, 0, stream>>>(H4, Wp, bp, out, N);
}

// Round 4
// 502.999 us; speedup vs baseline: 1.9420x; 1.1219x over previous
//
#include <hip/hip_runtime.h>
#include <hip/hip_bf16.h>

#define NNODES 20000
#define NEDGES 320000
#define XW 1005          // x row width: 1 + 1000 + 1 + 3
#define MP 20096         // 157 * 128 row-padded M

typedef __attribute__((ext_vector_type(8))) short short8;
typedef __attribute__((ext_vector_type(4))) float f32x4;
typedef __attribute__((ext_vector_type(4))) unsigned short u16x4;

typedef const __attribute__((address_space(1))) unsigned int gas_u32;
typedef __attribute__((address_space(3))) unsigned int las_u32;

__device__ inline void ld16(const unsigned short* g, unsigned short* l) {
    __builtin_amdgcn_global_load_lds((gas_u32*)g, (las_u32*)l, 16, 0, 0);
}

__device__ inline void split1(float v, unsigned short& h, unsigned short& l) {
    unsigned u = __float_as_uint(v);
    h = (unsigned short)(u >> 16);
    float hf = __uint_as_float(u & 0xffff0000u);
    l = (unsigned short)(__float_as_uint(v - hf) >> 16);
}

// ---------------- CSR build ----------------

__global__ void edge_deg_kernel(const int* __restrict__ ei, const float* __restrict__ ea,
                                float* __restrict__ deg, int* __restrict__ counts, int E) {
    int e = blockIdx.x * 256 + threadIdx.x;
    if (e >= E) return;
    int dst = ei[E + e];
    atomicAdd(&deg[dst], ea[e]);
    atomicAdd(&counts[dst], 1);
}

__global__ void dinv_kernel(const float* __restrict__ deg, float* __restrict__ dinv, int n) {
    int i = blockIdx.x * 256 + threadIdx.x;
    if (i >= n) return;
    float d = deg[i] + 1.0f;
    dinv[i] = 1.0f / sqrtf(d);
}

__global__ __launch_bounds__(1024) void scan_kernel(const int* __restrict__ counts,
                                                    int* __restrict__ offs, int n) {
    __shared__ int wsum[16];
    __shared__ int wpre[16];
    __shared__ int carry_s;
    int t = threadIdx.x;
    int lane = t & 63, wid = t >> 6;
    if (t == 0) carry_s = 0;
    __syncthreads();
    for (int base = 0; base < n; base += 1024) {
        int i = base + t;
        int v = (i < n) ? counts[i] : 0;
        int x = v;
#pragma unroll
        for (int d = 1; d < 64; d <<= 1) {
            int u = __shfl_up(x, d, 64);
            if (lane >= d) x += u;
        }
        if (lane == 63) wsum[wid] = x;
        __syncthreads();
        if (wid == 0) {
            int s = (lane < 16) ? wsum[lane] : 0;
#pragma unroll
            for (int d = 1; d < 16; d <<= 1) {
                int u = __shfl_up(s, d, 64);
                if (lane >= d) s += u;
            }
            if (lane < 16) wpre[lane] = s;
        }
        __syncthreads();
        int carry = carry_s;
        int prefix = carry + (wid > 0 ? wpre[wid - 1] : 0);
        if (i < n) offs[i] = prefix + x - v;   // exclusive
        __syncthreads();
        if (t == 1023) carry_s = prefix + x;
    }
    __syncthreads();
    if (t == 0) offs[n] = carry_s;
}

__global__ void scatter_kernel(const int* __restrict__ ei, const float* __restrict__ ea,
                               const float* __restrict__ dinv, const int* __restrict__ offs,
                               int* __restrict__ cursor, int* __restrict__ csr_src,
                               float* __restrict__ csr_norm, int E) {
    int e = blockIdx.x * 256 + threadIdx.x;
    if (e >= E) return;
    int src = ei[e];
    int dst = ei[E + e];
    int slot = offs[dst] + atomicAdd(&cursor[dst], 1);
    csr_src[slot] = src;
    csr_norm[slot] = dinv[src] * ea[e] * dinv[dst];
}

// ---------------- embedding indices ----------------

__global__ void idx_kernel(const float* __restrict__ x, int* __restrict__ idx8, int n) {
    int i = blockIdx.x * 256 + threadIdx.x;
    if (i >= n) return;
    const float* r = x + (size_t)i * XW;
    idx8[i * 8 + 0] = (int)(r[0] - 1.0f);
    idx8[i * 8 + 1] = (int)rintf(fabsf(r[1001]) * 10.0f);
    idx8[i * 8 + 2] = (int)r[1002];
    idx8[i * 8 + 3] = (int)r[1003];
    idx8[i * 8 + 4] = (int)r[1004];
}

// ---------------- table pre-GEMMs: T is (3 + 11 + 3*256) x 512 ----------------

__global__ __launch_bounds__(256) void tables_kernel(
    const float* __restrict__ layer_table, const float* __restrict__ rel_table,
    const float* __restrict__ color_table, const float* __restrict__ W1,
    float* __restrict__ T) {
    int g = blockIdx.x * 256 + threadIdx.x;
    if (g >= 782 * 512) return;
    int row = g >> 9, col = g & 511;
    float acc = 0.0f;
    if (row < 3) {
        for (int k = 0; k < 250; ++k)
            acc += layer_table[row * 250 + k] * W1[(size_t)k * 512 + col];
    } else if (row < 14) {
        int r = row - 3;
        for (int k = 0; k < 250; ++k)
            acc += rel_table[r * 250 + k] * W1[(size_t)(1250 + k) * 512 + col];
    } else {
        int r = row - 14;
        int j = r >> 8, v = r & 255;
        int base = 1500 + 85 * j;
        for (int k = 0; k < 85; ++k)
            acc += color_table[v * 85 + k] * W1[(size_t)(base + k) * 512 + col];
    }
    T[(size_t)row * 512 + col] = acc;
}

// ---------------- operand pre-split ----------------

// A1: x[:,1:1001] -> hi/lo bf16, [20000][1024] (k-pad zeroed)
__global__ __launch_bounds__(256) void a1_split_kernel(const float* __restrict__ x,
                                                       unsigned short* __restrict__ Ah,
                                                       unsigned short* __restrict__ Al) {
    int g = blockIdx.x * 256 + threadIdx.x;
    if (g >= NNODES * 256) return;
    int row = g >> 8, c4 = (g & 255) << 2;
    const float* xp = x + (size_t)row * XW + 1 + c4;
    u16x4 h, l;
#pragma unroll
    for (int i = 0; i < 4; ++i) {
        float v = (c4 + i < 1000) ? xp[i] : 0.0f;
        unsigned short hh, ll;
        split1(v, hh, ll);
        h[i] = (short)hh; l[i] = (short)ll;
    }
    *(u16x4*)&Ah[(size_t)row * 1024 + c4] = h;
    *(u16x4*)&Al[(size_t)row * 1024 + c4] = l;
}

// Bt: W[K][Ncols] (row offset koff) -> transposed hi/lo bf16 [Ncols][Kp]
__global__ __launch_bounds__(256) void bt_split_kernel(const float* __restrict__ W, int ldw,
                                                       int koff, int K, int Kp, int Ncols,
                                                       unsigned short* __restrict__ Bh,
                                                       unsigned short* __restrict__ Bl) {
    int g = blockIdx.x * 256 + threadIdx.x;
    int kp4 = Kp >> 2;
    if (g >= Ncols * kp4) return;
    int n = g / kp4, c4 = (g % kp4) << 2;
    u16x4 h, l;
#pragma unroll
    for (int i = 0; i < 4; ++i) {
        int k = c4 + i;
        float v = (k < K) ? W[(size_t)(koff + k) * ldw + n] : 0.0f;
        unsigned short hh, ll;
        split1(v, hh, ll);
        h[i] = (short)hh; l[i] = (short)ll;
    }
    *(u16x4*)&Bh[(size_t)n * Kp + c4] = h;
    *(u16x4*)&Bl[(size_t)n * Kp + c4] = l;
}

// ---------------- split-bf16 MFMA GEMM, async-LDS staging ----------------

template <int BN, bool EMB>
__global__ __launch_bounds__(256, 3) void gemm_split_kernel(
    const unsigned short* __restrict__ Ah, const unsigned short* __restrict__ Al, int Kp,
    const unsigned short* __restrict__ Bh, const unsigned short* __restrict__ Bl,
    float* __restrict__ C, int ldc, int M,
    const float* __restrict__ T, const int* __restrict__ idx8) {
    constexpr int NT = BN / 32;     // n-tiles per wave
    constexpr int BJ = BN / 64;     // B staging instrs per wave per plane
    __shared__ __align__(16) unsigned short sAh[128 * 32];
    __shared__ __align__(16) unsigned short sAl[128 * 32];
    __shared__ __align__(16) unsigned short sBh[BN * 32];
    __shared__ __align__(16) unsigned short sBl[BN * 32];

    const int t = threadIdx.x;
    const int lane = t & 63;
    const int w = t >> 6;
    const int wr = w >> 1, wc = w & 1;
    const int l15 = lane & 15, quad = lane >> 4;
    const int row0 = blockIdx.y * 128;
    const int col0 = blockIdx.x * BN;

    const int si_r = lane >> 2;                      // row within 16-row group
    const int si_s = lane & 3;                       // LDS chunk slot
    const int schunk = si_s ^ ((si_r >> 1) & 3);     // global chunk staged into slot
    const int sw = (quad ^ ((l15 >> 1) & 3)) * 8;    // fragment slot offset (ushorts)

    const unsigned short* gAh[2]; const unsigned short* gAl[2];
    unsigned short* dAh[2]; unsigned short* dAl[2];
#pragma unroll
    for (int j = 0; j < 2; ++j) {
        int ra = w * 32 + j * 16 + si_r;
        size_t e = (size_t)(row0 + ra) * Kp + schunk * 8;
        gAh[j] = Ah + e; gAl[j] = Al + e;
        dAh[j] = &sAh[(w * 32 + j * 16) * 32];
        dAl[j] = &sAl[(w * 32 + j * 16) * 32];
    }
    const unsigned short* gBh[BJ]; const unsigned short* gBl[BJ];
    unsigned short* dBh[BJ]; unsigned short* dBl[BJ];
#pragma unroll
    for (int j = 0; j < BJ; ++j) {
        int rb = w * (BN / 4) + j * 16 + si_r;
        size_t e = (size_t)(col0 + rb) * Kp + schunk * 8;
        gBh[j] = Bh + e; gBl[j] = Bl + e;
        dBh[j] = &sBh[(w * (BN / 4) + j * 16) * 32];
        dBl[j] = &sBl[(w * (BN / 4) + j * 16) * 32];
    }

    f32x4 acc[4][NT];
#pragma unroll
    for (int i = 0; i < 4; ++i)
#pragma unroll
        for (int j = 0; j < NT; ++j)
            acc[i][j] = (f32x4){0.f, 0.f, 0.f, 0.f};

    for (int kb = 0; kb < Kp; kb += 32) {
#pragma unroll
        for (int j = 0; j < 2; ++j) {
            ld16(gAh[j] + kb, dAh[j]);
            ld16(gAl[j] + kb, dAl[j]);
        }
#pragma unroll
        for (int j = 0; j < BJ; ++j) {
            ld16(gBh[j] + kb, dBh[j]);
            ld16(gBl[j] + kb, dBl[j]);
        }
        __syncthreads();

        short8 fah[4], fal[4], fbh[NT], fbl[NT];
#pragma unroll
        for (int mt = 0; mt < 4; ++mt) {
            int off = (wr * 64 + mt * 16 + l15) * 32 + sw;
            fah[mt] = *(const short8*)&sAh[off];
            fal[mt] = *(const short8*)&sAl[off];
        }
#pragma unroll
        for (int nt = 0; nt < NT; ++nt) {
            int off = (wc * (BN / 2) + nt * 16 + l15) * 32 + sw;
            fbh[nt] = *(const short8*)&sBh[off];
            fbl[nt] = *(const short8*)&sBl[off];
        }
#pragma unroll
        for (int mt = 0; mt < 4; ++mt)
#pragma unroll
            for (int nt = 0; nt < NT; ++nt)
                acc[mt][nt] = __builtin_amdgcn_mfma_f32_16x16x32_bf16(fah[mt], fbh[nt], acc[mt][nt], 0, 0, 0);
#pragma unroll
        for (int mt = 0; mt < 4; ++mt)
#pragma unroll
            for (int nt = 0; nt < NT; ++nt)
                acc[mt][nt] = __builtin_amdgcn_mfma_f32_16x16x32_bf16(fah[mt], fbl[nt], acc[mt][nt], 0, 0, 0);
#pragma unroll
        for (int mt = 0; mt < 4; ++mt)
#pragma unroll
            for (int nt = 0; nt < NT; ++nt)
                acc[mt][nt] = __builtin_amdgcn_mfma_f32_16x16x32_bf16(fal[mt], fbh[nt], acc[mt][nt], 0, 0, 0);
        __syncthreads();
    }

#pragma unroll
    for (int mt = 0; mt < 4; ++mt)
#pragma unroll
        for (int r = 0; r < 4; ++r) {
            int row = row0 + wr * 64 + mt * 16 + quad * 4 + r;
            if (row >= M) continue;
            if (EMB) {
                const int* ix = idx8 + row * 8;
                const float* t0 = T + (size_t)ix[0] * 512;
                const float* t1 = T + (size_t)(3 + ix[1]) * 512;
                const float* t2 = T + (size_t)(14 + ix[2]) * 512;
                const float* t3 = T + (size_t)(270 + ix[3]) * 512;
                const float* t4 = T + (size_t)(526 + ix[4]) * 512;
#pragma unroll
                for (int nt = 0; nt < NT; ++nt) {
                    int col = col0 + wc * (BN / 2) + nt * 16 + l15;
                    float e = t0[col] + t1[col] + t2[col] + t3[col] + t4[col];
                    C[(size_t)row * ldc + col] = acc[mt][nt][r] + e;
                }
            } else {
#pragma unroll
                for (int nt = 0; nt < NT; ++nt) {
                    int col = col0 + wc * (BN / 2) + nt * 16 + l15;
                    C[(size_t)row * ldc + col] = acc[mt][nt][r];
                }
            }
        }
}

// ---------------- column-sliced aggregation, XCD-pinned chunks ----------------
// agg commutes per feature column: chunk c of the feature dim is processed only
// by blocks with blockIdx.x % NCH == c. Under round-robin block->XCD dispatch
// this pins each chunk's gather working set (20000*CW*4 B) into 1-2 XCDs' L2.
// Edge metadata for the block's contiguous node range is staged into LDS once.

template <int F, int CW, bool SPLIT>
__global__ __launch_bounds__(256) void agg_cols_kernel(
    const float* __restrict__ H, const float* __restrict__ dinv,
    const int* __restrict__ offs, const int* __restrict__ csr_src,
    const float* __restrict__ csr_norm, const float* __restrict__ bias,
    float* __restrict__ outf, unsigned short* __restrict__ Hh,
    unsigned short* __restrict__ Hl, int n_nodes) {
    constexpr int LPN = CW / 4;        // lanes per node
    constexpr int NPB = 256 / LPN;     // nodes per block
    constexpr int NCH = F / CW;        // chunks (8 or 4)
    constexpr int ECAP = 2048;
    __shared__ int   se[ECAP];
    __shared__ float sn[ECAP];

    const int chunk = blockIdx.x & (NCH - 1);
    const int nb    = blockIdx.x / NCH;
    const int n0 = nb * NPB;
    const int n1 = min(n0 + NPB, n_nodes);
    if (n0 >= n_nodes) return;

    const int estart = offs[n0];
    const int eend   = offs[n1];
    const int ecnt   = eend - estart;
    const bool inlds = (ecnt <= ECAP);
    if (inlds) {
        for (int i = threadIdx.x; i < ecnt; i += 256) {
            se[i] = csr_src[estart + i];
            sn[i] = csr_norm[estart + i];
        }
    }
    __syncthreads();

    const int n = n0 + threadIdx.x / LPN;
    if (n >= n_nodes) return;
    const int lane = threadIdx.x % LPN;
    const int c = chunk * CW + lane * 4;

    float di = dinv[n];
    float s = di * di;
    float4 h = *(const float4*)(H + (size_t)n * F + c);
    float4 acc = make_float4(h.x * s, h.y * s, h.z * s, h.w * s);
    int e0 = offs[n], e1 = offs[n + 1];
    if (inlds) {
        for (int e = e0 - estart; e < e1 - estart; ++e) {
            int src = se[e];
            float w = sn[e];
            float4 v = *(const float4*)(H + (size_t)src * F + c);
            acc.x += v.x * w; acc.y += v.y * w; acc.z += v.z * w; acc.w += v.w * w;
        }
    } else {
        for (int e = e0; e < e1; ++e) {
            int src = csr_src[e];
            float w = csr_norm[e];
            float4 v = *(const float4*)(H + (size_t)src * F + c);
            acc.x += v.x * w; acc.y += v.y * w; acc.z += v.z * w; acc.w += v.w * w;
        }
    }
    float4 b = *(const float4*)(bias + c);
    acc.x += b.x; acc.y += b.y; acc.z += b.z; acc.w += b.w;
    acc.x = acc.x > 0.f ? acc.x : 0.01f * acc.x;
    acc.y = acc.y > 0.f ? acc.y : 0.01f * acc.y;
    acc.z = acc.z > 0.f ? acc.z : 0.01f * acc.z;
    acc.w = acc.w > 0.f ? acc.w : 0.01f * acc.w;
    if (SPLIT) {
        u16x4 hh, ll;
        unsigned short a, bb;
        split1(acc.x, a, bb); hh[0] = (short)a; ll[0] = (short)bb;
        split1(acc.y, a, bb); hh[1] = (short)a; ll[1] = (short)bb;
        split1(acc.z, a, bb); hh[2] = (short)a; ll[2] = (short)bb;
        split1(acc.w, a, bb); hh[3] = (short)a; ll[3] = (short)bb;
        *(u16x4*)(Hh + (size_t)n * F + c) = hh;
        *(u16x4*)(Hl + (size_t)n * F + c) = ll;
    } else {
        *(float4*)(outf + (size_t)n * F + c) = acc;
    }
}

// ---------------- final projection: out = h3 @ Wp + bp ----------------

__global__ void proj_kernel(const float* __restrict__ H, const float* __restrict__ Wp,
                            const float* __restrict__ bp, float* __restrict__ out, int n_nodes) {
    int t = blockIdx.x * 192 + threadIdx.x;
    int n = t / 3, j = t % 3;
    if (n >= n_nodes) return;
    float acc = bp[j];
    const float* h = H + (size_t)n * 64;
    for (int c = 0; c < 64; ++c) acc += h[c] * Wp[c * 3 + j];
    out[n * 3 + j] = acc;
}

// ---------------- launch ----------------

static inline size_t aln(size_t v) { return (v + 255) & ~(size_t)255; }

extern "C" void kernel_launch(void* const* d_in, const int* in_sizes, int n_in,
                              void* d_out, int out_size, void* d_ws, size_t ws_size,
                              hipStream_t stream) {
    const float* x           = (const float*)d_in[0];
    const int*   edge_index  = (const int*)d_in[1];
    const float* edge_attr   = (const float*)d_in[2];
    const float* layer_table = (const float*)d_in[3];
    const float* rel_table   = (const float*)d_in[4];
    const float* color_table = (const float*)d_in[5];
    const float* W1 = (const float*)d_in[6];
    const float* b1 = (const float*)d_in[7];
    const float* W2 = (const float*)d_in[8];
    const float* b2 = (const float*)d_in[9];
    const float* W3 = (const float*)d_in[10];
    const float* b3 = (const float*)d_in[11];
    const float* Wp = (const float*)d_in[12];
    const float* bp = (const float*)d_in[13];
    float* out = (float*)d_out;

    const int N = NNODES, E = NEDGES;

    char* p = (char*)d_ws;
    float* deg      = (float*)p; p += aln((size_t)N * 4);
    float* dinv     = (float*)p; p += aln((size_t)N * 4);
    float* T        = (float*)p; p += aln((size_t)782 * 512 * 4);
    float* csr_norm = (float*)p; p += aln((size_t)E * 4);
    float* C        = (float*)p; p += aln((size_t)MP * 512 * 4);
    unsigned short* BIG = (unsigned short*)p; p += aln((size_t)MP * 2048 * 2);
    unsigned short* Bt1h = (unsigned short*)p; p += aln((size_t)512 * 1024 * 2);
    unsigned short* Bt1l = (unsigned short*)p; p += aln((size_t)512 * 1024 * 2);
    unsigned short* Bt2h = (unsigned short*)p; p += aln((size_t)256 * 512 * 2);
    unsigned short* Bt2l = (unsigned short*)p; p += aln((size_t)256 * 512 * 2);
    unsigned short* Bt3h = (unsigned short*)p; p += aln((size_t)64 * 256 * 2);
    unsigned short* Bt3l = (unsigned short*)p; p += aln((size_t)64 * 256 * 2);
    int*   counts   = (int*)p;   p += aln((size_t)N * 4);
    int*   cursor   = (int*)p;   p += aln((size_t)N * 4);
    int*   csr_src  = (int*)p;   p += aln((size_t)E * 4);
    int*   idx8     = (int*)p;   p += aln((size_t)N * 8 * 4);
    int*   offs     = (int*)p;   p += aln((size_t)(N + 1) * 4);

    unsigned short* A1h = BIG;
    unsigned short* A1l = BIG + (size_t)MP * 1024;
    unsigned short* H2h = BIG;
    unsigned short* H2l = BIG + (size_t)MP * 512;
    unsigned short* H3h = BIG + (size_t)MP * 1024;
    unsigned short* H3l = BIG + (size_t)MP * 1024 + (size_t)MP * 256;
    float*          H4  = (float*)(BIG + (size_t)MP * 1536);

    hipMemsetAsync(deg, 0, (size_t)N * 4, stream);
    hipMemsetAsync(counts, 0, (size_t)N * 4, stream);
    hipMemsetAsync(cursor, 0, (size_t)N * 4, stream);

    edge_deg_kernel<<<(E + 255) / 256, 256, 0, stream>>>(edge_index, edge_attr, deg, counts, E);
    dinv_kernel<<<(N + 255) / 256, 256, 0, stream>>>(deg, dinv, N);
    scan_kernel<<<1, 1024, 0, stream>>>(counts, offs, N);
    scatter_kernel<<<(E + 255) / 256, 256, 0, stream>>>(edge_index, edge_attr, dinv, offs,
                                                        cursor, csr_src, csr_norm, E);
    idx_kernel<<<(N + 255) / 256, 256, 0, stream>>>(x, idx8, N);
    tables_kernel<<<(782 * 512 + 255) / 256, 256, 0, stream>>>(layer_table, rel_table,
                                                               color_table, W1, T);
    a1_split_kernel<<<(NNODES * 256) / 256, 256, 0, stream>>>(x, A1h, A1l);
    bt_split_kernel<<<(512 * 256 + 255) / 256, 256, 0, stream>>>(W1, 512, 250, 1000, 1024, 512, Bt1h, Bt1l);
    bt_split_kernel<<<(256 * 128 + 255) / 256, 256, 0, stream>>>(W2, 256, 0, 512, 512, 256, Bt2h, Bt2l);
    bt_split_kernel<<<(64 * 64 + 255) / 256, 256, 0, stream>>>(W3, 64, 0, 256, 256, 64, Bt3h, Bt3l);

    const int nrb = MP / 128;   // 157

    // layer 1
    {
        dim3 grid(512 / 128, nrb);
        gemm_split_kernel<128, true><<<grid, 256, 0, stream>>>(A1h, A1l, 1024, Bt1h, Bt1l,
                                                               C, 512, N, T, idx8);
        int nblocks = (N + 15) / 16;           // NPB=16
        agg_cols_kernel<512, 64, true><<<8 * nblocks, 256, 0, stream>>>(
            C, dinv, offs, csr_src, csr_norm, b1, nullptr, H2h, H2l, N);
    }
    // layer 2
    {
        dim3 grid(256 / 128, nrb);
        gemm_split_kernel<128, false><<<grid, 256, 0, stream>>>(H2h, H2l, 512, Bt2h, Bt2l,
                                                                C, 256, N, nullptr, nullptr);
        int nblocks = (N + 31) / 32;           // NPB=32
        agg_cols_kernel<256, 32, true><<<8 * nblocks, 256, 0, stream>>>(
            C, dinv, offs, csr_src, csr_norm, b2, nullptr, H3h, H3l, N);
    }
    // layer 3
    {
        dim3 grid(1, nrb);
        gemm_split_kernel<64, false><<<grid, 256, 0, stream>>>(H3h, H3l, 256, Bt3h, Bt3l,
                                                               C, 64, N, nullptr, nullptr);
        int nblocks = (N + 63) / 64;           // NPB=64
        agg_cols_kernel<64, 16, false><<<4 * nblocks, 256, 0, stream>>>(
            C, dinv, offs, csr_src, csr_norm, b3, H4, nullptr, nullptr, N);
    }
    // projection
    proj_kernel<<<(N * 3 + 191) / 192, 192, 0, stream>>>(H4, Wp, bp, out, N);
}

// Round 5
// 455.503 us; speedup vs baseline: 2.1445x; 1.1043x over previous
//
#include <hip/hip_runtime.h>
#include <hip/hip_bf16.h>

#define NNODES 20000
#define NEDGES 320000
#define XW 1005          // x row width: 1 + 1000 + 1 + 3
#define MP 20096         // 314 * 64 row-padded M

typedef __attribute__((ext_vector_type(8))) short short8;
typedef __attribute__((ext_vector_type(4))) float f32x4;
typedef __attribute__((ext_vector_type(4))) unsigned short u16x4;

typedef const __attribute__((address_space(1))) unsigned int gas_u32;
typedef __attribute__((address_space(3))) unsigned int las_u32;

__device__ inline void ld16(const unsigned short* g, unsigned short* l) {
    __builtin_amdgcn_global_load_lds((gas_u32*)g, (las_u32*)l, 16, 0, 0);
}

__device__ inline void split1(float v, unsigned short& h, unsigned short& l) {
    unsigned u = __float_as_uint(v);
    h = (unsigned short)(u >> 16);
    float hf = __uint_as_float(u & 0xffff0000u);
    l = (unsigned short)(__float_as_uint(v - hf) >> 16);
}

// ================= fused prep über-kernel =================
// independent jobs partitioned by blockIdx range (all 256-thread blocks):
//   [0,1250)      edge_deg: atomics into deg/counts
//   [1250,1329)   idx8
//   [1329,21329)  a1_split (block = one node row)
//   [21329,21841) bt_split W1
//   [21841,21969) bt_split W2
//   [21969,21985) bt_split W3
//   [21985,23549) tables
#define PB_EDGE  1250
#define PB_IDX   1329
#define PB_A1    21329
#define PB_BT1   21841
#define PB_BT2   21969
#define PB_BT3   21985
#define PB_TAB   23549

__device__ inline void bt_split_body(int g, const float* __restrict__ W, int ldw,
                                     int koff, int K, int Kp, int Ncols,
                                     unsigned short* __restrict__ Bh,
                                     unsigned short* __restrict__ Bl) {
    int kp4 = Kp >> 2;
    if (g >= Ncols * kp4) return;
    int n = g / kp4, c4 = (g % kp4) << 2;
    u16x4 h, l;
#pragma unroll
    for (int i = 0; i < 4; ++i) {
        int k = c4 + i;
        float v = (k < K) ? W[(size_t)(koff + k) * ldw + n] : 0.0f;
        unsigned short hh, ll;
        split1(v, hh, ll);
        h[i] = (short)hh; l[i] = (short)ll;
    }
    *(u16x4*)&Bh[(size_t)n * Kp + c4] = h;
    *(u16x4*)&Bl[(size_t)n * Kp + c4] = l;
}

__global__ __launch_bounds__(256) void prep_kernel(
    const float* __restrict__ x, const int* __restrict__ ei, const float* __restrict__ ea,
    const float* __restrict__ layer_table, const float* __restrict__ rel_table,
    const float* __restrict__ color_table,
    const float* __restrict__ W1, const float* __restrict__ W2, const float* __restrict__ W3,
    float* __restrict__ deg, int* __restrict__ counts, int* __restrict__ idx8,
    unsigned short* __restrict__ A1h, unsigned short* __restrict__ A1l,
    unsigned short* __restrict__ Bt1h, unsigned short* __restrict__ Bt1l,
    unsigned short* __restrict__ Bt2h, unsigned short* __restrict__ Bt2l,
    unsigned short* __restrict__ Bt3h, unsigned short* __restrict__ Bt3l,
    float* __restrict__ T) {
    const int b = blockIdx.x;
    const int t = threadIdx.x;
    if (b < PB_EDGE) {
        int e = b * 256 + t;
        if (e >= NEDGES) return;
        int dst = ei[NEDGES + e];
        atomicAdd(&deg[dst], ea[e]);
        atomicAdd(&counts[dst], 1);
    } else if (b < PB_IDX) {
        int i = (b - PB_EDGE) * 256 + t;
        if (i >= NNODES) return;
        const float* r = x + (size_t)i * XW;
        idx8[i * 8 + 0] = (int)(r[0] - 1.0f);
        idx8[i * 8 + 1] = (int)rintf(fabsf(r[1001]) * 10.0f);
        idx8[i * 8 + 2] = (int)r[1002];
        idx8[i * 8 + 3] = (int)r[1003];
        idx8[i * 8 + 4] = (int)r[1004];
    } else if (b < PB_A1) {
        int row = b - PB_IDX;                  // one block per node
        int c4 = t << 2;
        const float* xp = x + (size_t)row * XW + 1 + c4;
        u16x4 h, l;
#pragma unroll
        for (int i = 0; i < 4; ++i) {
            float v = (c4 + i < 1000) ? xp[i] : 0.0f;
            unsigned short hh, ll;
            split1(v, hh, ll);
            h[i] = (short)hh; l[i] = (short)ll;
        }
        *(u16x4*)&A1h[(size_t)row * 1024 + c4] = h;
        *(u16x4*)&A1l[(size_t)row * 1024 + c4] = l;
    } else if (b < PB_BT1) {
        bt_split_body((b - PB_A1) * 256 + t, W1, 512, 250, 1000, 1024, 512, Bt1h, Bt1l);
    } else if (b < PB_BT2) {
        bt_split_body((b - PB_BT1) * 256 + t, W2, 256, 0, 512, 512, 256, Bt2h, Bt2l);
    } else if (b < PB_BT3) {
        bt_split_body((b - PB_BT2) * 256 + t, W3, 64, 0, 256, 256, 64, Bt3h, Bt3l);
    } else {
        int g = (b - PB_BT3) * 256 + t;
        if (g >= 782 * 512) return;
        int row = g >> 9, col = g & 511;
        float acc = 0.0f;
        if (row < 3) {
            for (int k = 0; k < 250; ++k)
                acc += layer_table[row * 250 + k] * W1[(size_t)k * 512 + col];
        } else if (row < 14) {
            int r = row - 3;
            for (int k = 0; k < 250; ++k)
                acc += rel_table[r * 250 + k] * W1[(size_t)(1250 + k) * 512 + col];
        } else {
            int r = row - 14;
            int j = r >> 8, v = r & 255;
            int base = 1500 + 85 * j;
            for (int k = 0; k < 85; ++k)
                acc += color_table[v * 85 + k] * W1[(size_t)(base + k) * 512 + col];
        }
        T[(size_t)row * 512 + col] = acc;
    }
}

// ================= 3-phase parallel scan (+ dinv folded into phase 1) =================

__global__ __launch_bounds__(1024) void scan_p1_kernel(const int* __restrict__ counts,
                                                       int* __restrict__ bsum,
                                                       const float* __restrict__ deg,
                                                       float* __restrict__ dinv, int n) {
    int b = blockIdx.x;
    if (b < 20) {
        __shared__ int ws[16];
        int t = threadIdx.x, lane = t & 63, wid = t >> 6;
        int i = b * 1024 + t;
        int v = (i < n) ? counts[i] : 0;
#pragma unroll
        for (int d = 32; d; d >>= 1) v += __shfl_down(v, d, 64);
        if (lane == 0) ws[wid] = v;
        __syncthreads();
        if (wid == 0) {
            int s = (lane < 16) ? ws[lane] : 0;
#pragma unroll
            for (int d = 8; d; d >>= 1) s += __shfl_down(s, d, 64);
            if (lane == 0) bsum[b] = s;
        }
    } else {
        int i = (b - 20) * 1024 + threadIdx.x;
        if (i < n) { float d = deg[i] + 1.0f; dinv[i] = 1.0f / sqrtf(d); }
    }
}

__global__ void scan_p2_kernel(const int* __restrict__ bsum, int* __restrict__ boffs,
                               int* __restrict__ offs, int n, int nb) {
    int lane = threadIdx.x;   // 64 threads
    int v = (lane < nb) ? bsum[lane] : 0;
    int xv = v;
#pragma unroll
    for (int d = 1; d < 64; d <<= 1) {
        int u = __shfl_up(xv, d, 64);
        if (lane >= d) xv += u;
    }
    if (lane < nb) boffs[lane] = xv - v;
    if (lane == nb - 1) offs[n] = xv;
}

__global__ __launch_bounds__(1024) void scan_p3_kernel(const int* __restrict__ counts,
                                                       const int* __restrict__ boffs,
                                                       int* __restrict__ offs, int n) {
    __shared__ int wsum[16], wpre[16];
    int t = threadIdx.x, lane = t & 63, wid = t >> 6;
    int i = blockIdx.x * 1024 + t;
    int v = (i < n) ? counts[i] : 0;
    int xv = v;
#pragma unroll
    for (int d = 1; d < 64; d <<= 1) {
        int u = __shfl_up(xv, d, 64);
        if (lane >= d) xv += u;
    }
    if (lane == 63) wsum[wid] = xv;
    __syncthreads();
    if (wid == 0) {
        int s = (lane < 16) ? wsum[lane] : 0;
#pragma unroll
        for (int d = 1; d < 16; d <<= 1) {
            int u = __shfl_up(s, d, 64);
            if (lane >= d) s += u;
        }
        if (lane < 16) wpre[lane] = s;
    }
    __syncthreads();
    int prefix = boffs[blockIdx.x] + (wid > 0 ? wpre[wid - 1] : 0);
    if (i < n) offs[i] = prefix + xv - v;
}

__global__ void scatter_kernel(const int* __restrict__ ei, const float* __restrict__ ea,
                               const float* __restrict__ dinv, const int* __restrict__ offs,
                               int* __restrict__ cursor, int* __restrict__ csr_src,
                               float* __restrict__ csr_norm, int E) {
    int e = blockIdx.x * 256 + threadIdx.x;
    if (e >= E) return;
    int src = ei[e];
    int dst = ei[E + e];
    int slot = offs[dst] + atomicAdd(&cursor[dst], 1);
    csr_src[slot] = src;
    csr_norm[slot] = dinv[src] * ea[e] * dinv[dst];
}

// ================= split-bf16 MFMA GEMM, BM=64, XCD-swizzled flat grid =================
// C[M,N] = (Ah+Al)[M,Kp] @ (Bh+Bl)^T[Kp,N], 3 MFMA passes (hh+hl+lh).
// 256 thr = 4 waves (2x2); wave = 32 rows x BN/2 cols of 16x16x32 tiles.
// Flat grid; tile = (bid&7)*per + bid>>3 keeps all column-blocks of a row band
// on one XCD (A-tile fetched once per XCD; B is L2-resident).

template <int BN, int NCB, bool EMB>
__global__ __launch_bounds__(256, 4) void gemm_split_kernel(
    const unsigned short* __restrict__ Ah, const unsigned short* __restrict__ Al, int Kp,
    const unsigned short* __restrict__ Bh, const unsigned short* __restrict__ Bl,
    float* __restrict__ C, int ldc, int M,
    const float* __restrict__ T, const int* __restrict__ idx8) {
    constexpr int NT = BN / 32;     // n-tiles per wave
    constexpr int BJ = BN / 64;     // B staging instrs per wave per plane
    __shared__ __align__(16) unsigned short sAh[64 * 32];
    __shared__ __align__(16) unsigned short sAl[64 * 32];
    __shared__ __align__(16) unsigned short sBh[BN * 32];
    __shared__ __align__(16) unsigned short sBl[BN * 32];

    const int t = threadIdx.x;
    const int lane = t & 63;
    const int w = t >> 6;
    const int wr = w >> 1, wc = w & 1;
    const int l15 = lane & 15, quad = lane >> 4;

    // XCD-swizzled tile mapping
    const int total = gridDim.x;
    const int per = total >> 3;
    const int bid = blockIdx.x;
    const int tile = (bid < (per << 3)) ? ((bid & 7) * per + (bid >> 3)) : bid;
    const int row0 = (tile / NCB) * 64;
    const int col0 = (tile % NCB) * BN;

    const int si_r = lane >> 2;                      // row within 16-row group
    const int si_s = lane & 3;                       // LDS chunk slot
    const int schunk = si_s ^ ((si_r >> 1) & 3);     // global chunk staged into slot
    const int sw = (quad ^ ((l15 >> 1) & 3)) * 8;    // fragment slot offset (ushorts)

    // staging pointers: A 64 rows = 4 waves x 16
    const unsigned short* gAh; const unsigned short* gAl;
    unsigned short* dAh; unsigned short* dAl;
    {
        int ra = w * 16 + si_r;
        size_t e = (size_t)(row0 + ra) * Kp + schunk * 8;
        gAh = Ah + e; gAl = Al + e;
        dAh = &sAh[(w * 16) * 32];
        dAl = &sAl[(w * 16) * 32];
    }
    const unsigned short* gBh[BJ]; const unsigned short* gBl[BJ];
    unsigned short* dBh[BJ]; unsigned short* dBl[BJ];
#pragma unroll
    for (int j = 0; j < BJ; ++j) {
        int rb = w * (BN / 4) + j * 16 + si_r;
        size_t e = (size_t)(col0 + rb) * Kp + schunk * 8;
        gBh[j] = Bh + e; gBl[j] = Bl + e;
        dBh[j] = &sBh[(w * (BN / 4) + j * 16) * 32];
        dBl[j] = &sBl[(w * (BN / 4) + j * 16) * 32];
    }

    f32x4 acc[2][NT];
#pragma unroll
    for (int i = 0; i < 2; ++i)
#pragma unroll
        for (int j = 0; j < NT; ++j)
            acc[i][j] = (f32x4){0.f, 0.f, 0.f, 0.f};

    for (int kb = 0; kb < Kp; kb += 32) {
        ld16(gAh + kb, dAh);
        ld16(gAl + kb, dAl);
#pragma unroll
        for (int j = 0; j < BJ; ++j) {
            ld16(gBh[j] + kb, dBh[j]);
            ld16(gBl[j] + kb, dBl[j]);
        }
        __syncthreads();

        short8 fah[2], fal[2], fbh[NT], fbl[NT];
#pragma unroll
        for (int mt = 0; mt < 2; ++mt) {
            int off = (wr * 32 + mt * 16 + l15) * 32 + sw;
            fah[mt] = *(const short8*)&sAh[off];
            fal[mt] = *(const short8*)&sAl[off];
        }
#pragma unroll
        for (int nt = 0; nt < NT; ++nt) {
            int off = (wc * (BN / 2) + nt * 16 + l15) * 32 + sw;
            fbh[nt] = *(const short8*)&sBh[off];
            fbl[nt] = *(const short8*)&sBl[off];
        }
#pragma unroll
        for (int mt = 0; mt < 2; ++mt)
#pragma unroll
            for (int nt = 0; nt < NT; ++nt)
                acc[mt][nt] = __builtin_amdgcn_mfma_f32_16x16x32_bf16(fah[mt], fbh[nt], acc[mt][nt], 0, 0, 0);
#pragma unroll
        for (int mt = 0; mt < 2; ++mt)
#pragma unroll
            for (int nt = 0; nt < NT; ++nt)
                acc[mt][nt] = __builtin_amdgcn_mfma_f32_16x16x32_bf16(fah[mt], fbl[nt], acc[mt][nt], 0, 0, 0);
#pragma unroll
        for (int mt = 0; mt < 2; ++mt)
#pragma unroll
            for (int nt = 0; nt < NT; ++nt)
                acc[mt][nt] = __builtin_amdgcn_mfma_f32_16x16x32_bf16(fal[mt], fbh[nt], acc[mt][nt], 0, 0, 0);
        __syncthreads();
    }

    // epilogue: C/D layout col=lane&15, row=quad*4+r  (+ fused embedding add)
#pragma unroll
    for (int mt = 0; mt < 2; ++mt)
#pragma unroll
        for (int r = 0; r < 4; ++r) {
            int row = row0 + wr * 32 + mt * 16 + quad * 4 + r;
            if (row >= M) continue;
            if (EMB) {
                const int* ix = idx8 + row * 8;
                const float* t0 = T + (size_t)ix[0] * 512;
                const float* t1 = T + (size_t)(3 + ix[1]) * 512;
                const float* t2 = T + (size_t)(14 + ix[2]) * 512;
                const float* t3 = T + (size_t)(270 + ix[3]) * 512;
                const float* t4 = T + (size_t)(526 + ix[4]) * 512;
#pragma unroll
                for (int nt = 0; nt < NT; ++nt) {
                    int col = col0 + wc * (BN / 2) + nt * 16 + l15;
                    float e = t0[col] + t1[col] + t2[col] + t3[col] + t4[col];
                    C[(size_t)row * ldc + col] = acc[mt][nt][r] + e;
                }
            } else {
#pragma unroll
                for (int nt = 0; nt < NT; ++nt) {
                    int col = col0 + wc * (BN / 2) + nt * 16 + l15;
                    C[(size_t)row * ldc + col] = acc[mt][nt][r];
                }
            }
        }
}

// ================= column-sliced aggregation, XCD-pinned chunks =================

template <int F, int CW, bool SPLIT>
__global__ __launch_bounds__(256) void agg_cols_kernel(
    const float* __restrict__ H, const float* __restrict__ dinv,
    const int* __restrict__ offs, const int* __restrict__ csr_src,
    const float* __restrict__ csr_norm, const float* __restrict__ bias,
    float* __restrict__ outf, unsigned short* __restrict__ Hh,
    unsigned short* __restrict__ Hl, int n_nodes) {
    constexpr int LPN = CW / 4;        // lanes per node
    constexpr int NPB = 256 / LPN;     // nodes per block
    constexpr int NCH = F / CW;        // chunks
    constexpr int ECAP = 2048;
    __shared__ int   se[ECAP];
    __shared__ float sn[ECAP];

    const int chunk = blockIdx.x & (NCH - 1);
    const int nb    = blockIdx.x / NCH;
    const int n0 = nb * NPB;
    const int n1 = min(n0 + NPB, n_nodes);
    if (n0 >= n_nodes) return;

    const int estart = offs[n0];
    const int eend   = offs[n1];
    const int ecnt   = eend - estart;
    const bool inlds = (ecnt <= ECAP);
    if (inlds) {
        for (int i = threadIdx.x; i < ecnt; i += 256) {
            se[i] = csr_src[estart + i];
            sn[i] = csr_norm[estart + i];
        }
    }
    __syncthreads();

    const int n = n0 + threadIdx.x / LPN;
    if (n >= n_nodes) return;
    const int lane = threadIdx.x % LPN;
    const int c = chunk * CW + lane * 4;

    float di = dinv[n];
    float s = di * di;
    float4 h = *(const float4*)(H + (size_t)n * F + c);
    float4 acc = make_float4(h.x * s, h.y * s, h.z * s, h.w * s);
    int e0 = offs[n], e1 = offs[n + 1];
    if (inlds) {
        for (int e = e0 - estart; e < e1 - estart; ++e) {
            int src = se[e];
            float w = sn[e];
            float4 v = *(const float4*)(H + (size_t)src * F + c);
            acc.x += v.x * w; acc.y += v.y * w; acc.z += v.z * w; acc.w += v.w * w;
        }
    } else {
        for (int e = e0; e < e1; ++e) {
            int src = csr_src[e];
            float w = csr_norm[e];
            float4 v = *(const float4*)(H + (size_t)src * F + c);
            acc.x += v.x * w; acc.y += v.y * w; acc.z += v.z * w; acc.w += v.w * w;
        }
    }
    float4 b = *(const float4*)(bias + c);
    acc.x += b.x; acc.y += b.y; acc.z += b.z; acc.w += b.w;
    acc.x = acc.x > 0.f ? acc.x : 0.01f * acc.x;
    acc.y = acc.y > 0.f ? acc.y : 0.01f * acc.y;
    acc.z = acc.z > 0.f ? acc.z : 0.01f * acc.z;
    acc.w = acc.w > 0.f ? acc.w : 0.01f * acc.w;
    if (SPLIT) {
        u16x4 hh, ll;
        unsigned short a, bb;
        split1(acc.x, a, bb); hh[0] = (short)a; ll[0] = (short)bb;
        split1(acc.y, a, bb); hh[1] = (short)a; ll[1] = (short)bb;
        split1(acc.z, a, bb); hh[2] = (short)a; ll[2] = (short)bb;
        split1(acc.w, a, bb); hh[3] = (short)a; ll[3] = (short)bb;
        *(u16x4*)(Hh + (size_t)n * F + c) = hh;
        *(u16x4*)(Hl + (size_t)n * F + c) = ll;
    } else {
        *(float4*)(outf + (size_t)n * F + c) = acc;
    }
}

// ================= final projection =================

__global__ void proj_kernel(const float* __restrict__ H, const float* __restrict__ Wp,
                            const float* __restrict__ bp, float* __restrict__ out, int n_nodes) {
    int t = blockIdx.x * 192 + threadIdx.x;
    int n = t / 3, j = t % 3;
    if (n >= n_nodes) return;
    float acc = bp[j];
    const float* h = H + (size_t)n * 64;
    for (int c = 0; c < 64; ++c) acc += h[c] * Wp[c * 3 + j];
    out[n * 3 + j] = acc;
}

// ================= launch =================

static inline size_t aln(size_t v) { return (v + 255) & ~(size_t)255; }

extern "C" void kernel_launch(void* const* d_in, const int* in_sizes, int n_in,
                              void* d_out, int out_size, void* d_ws, size_t ws_size,
                              hipStream_t stream) {
    const float* x           = (const float*)d_in[0];
    const int*   edge_index  = (const int*)d_in[1];
    const float* edge_attr   = (const float*)d_in[2];
    const float* layer_table = (const float*)d_in[3];
    const float* rel_table   = (const float*)d_in[4];
    const float* color_table = (const float*)d_in[5];
    const float* W1 = (const float*)d_in[6];
    const float* b1 = (const float*)d_in[7];
    const float* W2 = (const float*)d_in[8];
    const float* b2 = (const float*)d_in[9];
    const float* W3 = (const float*)d_in[10];
    const float* b3 = (const float*)d_in[11];
    const float* Wp = (const float*)d_in[12];
    const float* bp = (const float*)d_in[13];
    float* out = (float*)d_out;

    const int N = NNODES, E = NEDGES;

    char* p = (char*)d_ws;
    // zero region: deg + counts + cursor contiguous -> single memset
    float* deg      = (float*)p;
    int*   counts   = (int*)(p + (size_t)N * 4);
    int*   cursor   = (int*)(p + (size_t)N * 8);     p += aln((size_t)N * 12);
    float* dinv     = (float*)p; p += aln((size_t)N * 4);
    float* T        = (float*)p; p += aln((size_t)782 * 512 * 4);
    float* csr_norm = (float*)p; p += aln((size_t)E * 4);
    float* C        = (float*)p; p += aln((size_t)MP * 512 * 4);
    unsigned short* BIG = (unsigned short*)p; p += aln((size_t)MP * 2048 * 2);
    unsigned short* Bt1h = (unsigned short*)p; p += aln((size_t)512 * 1024 * 2);
    unsigned short* Bt1l = (unsigned short*)p; p += aln((size_t)512 * 1024 * 2);
    unsigned short* Bt2h = (unsigned short*)p; p += aln((size_t)256 * 512 * 2);
    unsigned short* Bt2l = (unsigned short*)p; p += aln((size_t)256 * 512 * 2);
    unsigned short* Bt3h = (unsigned short*)p; p += aln((size_t)64 * 256 * 2);
    unsigned short* Bt3l = (unsigned short*)p; p += aln((size_t)64 * 256 * 2);
    int*   csr_src  = (int*)p;   p += aln((size_t)E * 4);
    int*   idx8     = (int*)p;   p += aln((size_t)N * 8 * 4);
    int*   offs     = (int*)p;   p += aln((size_t)(N + 1) * 4);
    int*   bsum     = (int*)p;   p += aln((size_t)32 * 4);
    int*   boffs    = (int*)p;   p += aln((size_t)32 * 4);

    unsigned short* A1h = BIG;
    unsigned short* A1l = BIG + (size_t)MP * 1024;
    unsigned short* H2h = BIG;
    unsigned short* H2l = BIG + (size_t)MP * 512;
    unsigned short* H3h = BIG + (size_t)MP * 1024;
    unsigned short* H3l = BIG + (size_t)MP * 1024 + (size_t)MP * 256;
    float*          H4  = (float*)(BIG + (size_t)MP * 1536);

    hipMemsetAsync(deg, 0, (size_t)N * 12, stream);

    prep_kernel<<<PB_TAB, 256, 0, stream>>>(
        x, edge_index, edge_attr, layer_table, rel_table, color_table,
        W1, W2, W3, deg, counts, idx8,
        A1h, A1l, Bt1h, Bt1l, Bt2h, Bt2l, Bt3h, Bt3l, T);

    scan_p1_kernel<<<40, 1024, 0, stream>>>(counts, bsum, deg, dinv, N);
    scan_p2_kernel<<<1, 64, 0, stream>>>(bsum, boffs, offs, N, 20);
    scan_p3_kernel<<<20, 1024, 0, stream>>>(counts, boffs, offs, N);
    scatter_kernel<<<(E + 255) / 256, 256, 0, stream>>>(edge_index, edge_attr, dinv, offs,
                                                        cursor, csr_src, csr_norm, E);

    const int nrb = MP / 64;   // 314 row bands

    // layer 1
    {
        gemm_split_kernel<128, 4, true><<<nrb * 4, 256, 0, stream>>>(
            A1h, A1l, 1024, Bt1h, Bt1l, C, 512, N, T, idx8);
        int nblocks = (N + 15) / 16;           // NPB=16
        agg_cols_kernel<512, 64, true><<<8 * nblocks, 256, 0, stream>>>(
            C, dinv, offs, csr_src, csr_norm, b1, nullptr, H2h, H2l, N);
    }
    // layer 2
    {
        gemm_split_kernel<128, 2, false><<<nrb * 2, 256, 0, stream>>>(
            H2h, H2l, 512, Bt2h, Bt2l, C, 256, N, nullptr, nullptr);
        int nblocks = (N + 31) / 32;           // NPB=32
        agg_cols_kernel<256, 32, true><<<8 * nblocks, 256, 0, stream>>>(
            C, dinv, offs, csr_src, csr_norm, b2, nullptr, H3h, H3l, N);
    }
    // layer 3
    {
        gemm_split_kernel<64, 1, false><<<nrb, 256, 0, stream>>>(
            H3h, H3l, 256, Bt3h, Bt3l, C, 64, N, nullptr, nullptr);
        int nblocks = (N + 63) / 64;           // NPB=64
        agg_cols_kernel<64, 16, false><<<4 * nblocks, 256, 0, stream>>>(
            C, dinv, offs, csr_src, csr_norm, b3, H4, nullptr, nullptr, N);
    }
    // projection
    proj_kernel<<<(N * 3 + 191) / 192, 192, 0, stream>>>(H4, Wp, bp, out, N);
}